// Round 5
// baseline (3682.131 us; speedup 1.0000x reference)
//
#include <hip/hip_runtime.h>
#include <hip/hip_bf16.h>
#include <cstdint>
#include <cstddef>
#include <math.h>

#define B_DIM 1024
#define H_DIM 4096
#define D_DIM 65536
#define K_TOP 64
#define CAND_CAP 512
#define RECOMP 128
#define COLLECT_THRESH 2.8f

typedef float f32x4 __attribute__((ext_vector_type(4)));
typedef __bf16 bf16x8 __attribute__((ext_vector_type(8)));
typedef unsigned short u16x8 __attribute__((ext_vector_type(8)));

__device__ inline unsigned short f2bf(float f) {
    unsigned int u = __float_as_uint(f);
    unsigned int r = u + 0x7FFFu + ((u >> 16) & 1u);   // RNE
    return (unsigned short)(r >> 16);
}

// ---------------- Kernel 1: x_centered -> bf16 ----------------
__global__ void convert_x_kernel(const float* __restrict__ x,
                                 const float* __restrict__ pre_bias,
                                 unsigned short* __restrict__ xc) {
    int i = blockIdx.x * blockDim.x + threadIdx.x;      // quad index, total B*H/4
    float4 v = *(const float4*)&x[(size_t)i * 4];
    int h = (i * 4) & (H_DIM - 1);
    float4 pb = *(const float4*)&pre_bias[h];
    ushort4 o;
    o.x = f2bf(v.x - pb.x);
    o.y = f2bf(v.y - pb.y);
    o.z = f2bf(v.z - pb.z);
    o.w = f2bf(v.w - pb.w);
    *(ushort4*)&xc[(size_t)i * 4] = o;
}

// ---------------- Kernel 2: bf16 MFMA GEMM  pre_act = xc @ W_enc^T + b_enc ----------------
// T2 XOR swizzle: 16B slot s of row r lives at slot s^(r&7). Kills the 16-way
// ds_read_b128 bank conflict of 128B-row tiles (SQ_LDS_BANK_CONFLICT 1.5e8).
#define G_BM 256
#define G_BN 128
#define G_BK 64

__global__ void __launch_bounds__(256) gemm_enc_kernel(
        const unsigned short* __restrict__ A,    // xc bf16 [B_DIM][H_DIM]
        const float* __restrict__ Wenc,          // [D_DIM][H_DIM] f32
        const float* __restrict__ b_enc,         // [D_DIM]
        float* __restrict__ pre_act) {           // [B_DIM][D_DIM]
    __shared__ __align__(16) unsigned short sA[G_BM * G_BK];
    __shared__ __align__(16) unsigned short sB[G_BN * G_BK];

    const int tid = threadIdx.x;
    const int w = tid >> 6;
    const int l = tid & 63;
    const int m0 = blockIdx.x * G_BM;        // m fast -> concurrent blocks share W_enc panel
    const int n0 = blockIdx.y * G_BN;
    const int wm = w >> 1, wn = w & 1;
    const int lrow8 = l >> 3, lseg = l & 7;
    const int sw_seg = lseg ^ lrow8;         // write-side swizzle (row&7 == l>>3 for our tiling)

    f32x4 acc[8][4] = {};

    for (int k0 = 0; k0 < H_DIM; k0 += G_BK) {
        // stage A (bf16, already converted): linear LDS dest + pre-swizzled global source
#if __has_builtin(__builtin_amdgcn_global_load_lds)
        #pragma unroll
        for (int i = 0; i < 8; i++) {
            int row = w * 64 + i * 8 + lrow8;                 // row&7 == lrow8
            const unsigned short* src = &A[(size_t)(m0 + row) * H_DIM + k0 + sw_seg * 8];
            __builtin_amdgcn_global_load_lds(
                (const __attribute__((address_space(1))) unsigned int*)src,
                (__attribute__((address_space(3))) unsigned int*)&sA[(w * 64 + i * 8) * G_BK],
                16, 0, 0);
        }
#else
        #pragma unroll
        for (int i = 0; i < 8; i++) {
            int row = w * 64 + i * 8 + lrow8;
            uint4 d = *(const uint4*)&A[(size_t)(m0 + row) * H_DIM + k0 + lseg * 8];
            *(uint4*)&sA[row * G_BK + sw_seg * 8] = d;
        }
#endif
        // stage B with f32->bf16 convert, swizzled ds_write
        #pragma unroll
        for (int i = 0; i < 4; i++) {
            int row = w * 32 + i * 8 + lrow8;                 // row&7 == lrow8
            const float* src = &Wenc[(size_t)(n0 + row) * H_DIM + k0 + lseg * 8];
            float4 f0 = *(const float4*)src;
            float4 f1 = *(const float4*)(src + 4);
            u16x8 o;
            o[0] = f2bf(f0.x); o[1] = f2bf(f0.y); o[2] = f2bf(f0.z); o[3] = f2bf(f0.w);
            o[4] = f2bf(f1.x); o[5] = f2bf(f1.y); o[6] = f2bf(f1.z); o[7] = f2bf(f1.w);
            *(u16x8*)&sB[row * G_BK + sw_seg * 8] = o;
        }
        __syncthreads();

        #pragma unroll
        for (int ks = 0; ks < 2; ks++) {
            const int slot = ks * 4 + (l >> 4);               // 16B slot within row
            const int rslot = (slot ^ (l & 7)) * 8;           // read-side swizzle (r&7 == l&7)
            bf16x8 bfr[4];
            #pragma unroll
            for (int nj = 0; nj < 4; nj++) {
                int r = wn * 64 + nj * 16 + (l & 15);
                bfr[nj] = *(bf16x8*)&sB[r * G_BK + rslot];
            }
            #pragma unroll
            for (int mi = 0; mi < 8; mi++) {
                int r = wm * 128 + mi * 16 + (l & 15);
                bf16x8 afr = *(bf16x8*)&sA[r * G_BK + rslot];
                #pragma unroll
                for (int nj = 0; nj < 4; nj++)
                    acc[mi][nj] = __builtin_amdgcn_mfma_f32_16x16x32_bf16(afr, bfr[nj], acc[mi][nj], 0, 0, 0);
            }
        }
        __syncthreads();
    }

    const int lc = l & 15, lr4 = (l >> 4) * 4;
    #pragma unroll
    for (int nj = 0; nj < 4; nj++) {
        int col = n0 + wn * 64 + nj * 16 + lc;
        float bias = b_enc[col];
        #pragma unroll
        for (int mi = 0; mi < 8; mi++) {
            int row = m0 + wm * 128 + mi * 16 + lr4;
            #pragma unroll
            for (int e = 0; e < 4; e++) {
                pre_act[(size_t)(row + e) * D_DIM + col] = acc[mi][nj][e] + bias;
            }
        }
    }
}

// ---------------- Kernel 3: collect candidates (pre_act > THRESH) ----------------
__global__ void collect_kernel(const float* __restrict__ pre_act,
                               int* __restrict__ cnt,
                               int* __restrict__ cidx,
                               float* __restrict__ cval) {
    int i = blockIdx.x * blockDim.x + threadIdx.x;   // quad index over B*D/4
    float4 v = *(const float4*)&pre_act[(size_t)i * 4];
    float fv[4] = {v.x, v.y, v.z, v.w};
    int base = i * 4;
    #pragma unroll
    for (int e = 0; e < 4; e++) {
        if (fv[e] > COLLECT_THRESH) {
            int idx = base + e;
            int b = idx >> 16;               // D_DIM = 2^16
            int d = idx & (D_DIM - 1);
            int p = atomicAdd(&cnt[b], 1);
            if (p < CAND_CAP) {
                cidx[b * CAND_CAP + p] = d;
                cval[b * CAND_CAP + p] = fv[e];
            }
        }
    }
}

// ---------------- Kernel 4: approx sort -> f64 recompute (WITH bias) -> exact top-64 ----------------
__global__ void __launch_bounds__(256) select_topk_kernel(
        const float* __restrict__ x, const float* __restrict__ pre_bias,
        const float* __restrict__ Wenc, const float* __restrict__ b_enc,
        const int* __restrict__ cnt, const int* __restrict__ cidx, const float* __restrict__ cval,
        float* __restrict__ out_vals, float* __restrict__ out_idx) {
    __shared__ float s_val[CAND_CAP];
    __shared__ int   s_idx[CAND_CAP];
    __shared__ __align__(16) float s_x[H_DIM];
    __shared__ double s_dv[RECOMP];
    __shared__ int    s_di[RECOMP];

    const int b = blockIdx.x;
    const int tid = threadIdx.x;

    for (int i = tid; i < H_DIM / 4; i += 256) {
        float4 xv = *(const float4*)&x[(size_t)b * H_DIM + i * 4];
        float4 pb = *(const float4*)&pre_bias[i * 4];
        xv.x -= pb.x; xv.y -= pb.y; xv.z -= pb.z; xv.w -= pb.w;
        *(float4*)&s_x[i * 4] = xv;
    }
    const int n = min(cnt[b], CAND_CAP);
    for (int i = tid; i < CAND_CAP; i += 256) {
        if (i < n) { s_val[i] = cval[b * CAND_CAP + i]; s_idx[i] = cidx[b * CAND_CAP + i]; }
        else       { s_val[i] = -1e30f;                 s_idx[i] = 0x7FFFFFFF; }
    }
    __syncthreads();

    // bitonic sort 512 by approx value desc, tie idx asc
    for (int k = 2; k <= CAND_CAP; k <<= 1) {
        for (int j = k >> 1; j > 0; j >>= 1) {
            int p = tid;
            int i1 = (p / j) * 2 * j + (p % j);
            int i2 = i1 + j;
            bool up = ((i1 & k) == 0);
            float v1 = s_val[i1], v2 = s_val[i2];
            int  d1 = s_idx[i1],  d2 = s_idx[i2];
            bool before12 = (v1 > v2) || (v1 == v2 && d1 < d2);
            bool before21 = (v2 > v1) || (v2 == v1 && d2 < d1);
            bool sw = up ? before21 : before12;
            __syncthreads();
            if (sw) { s_val[i1] = v2; s_val[i2] = v1; s_idx[i1] = d2; s_idx[i2] = d1; }
            __syncthreads();
        }
    }

    // f64 recompute of the top-RECOMP approx candidates, INCLUDING b_enc
    const int T = min(RECOMP, n);
    double dv = -1e300;
    int di = 0x7FFFFFFF;
    if (tid < T) {
        di = s_idx[tid];
        const float* wr = &Wenc[(size_t)di * H_DIM];
        double a0 = 0, a1 = 0, a2 = 0, a3 = 0;
        for (int h = 0; h < H_DIM; h += 4) {
            float4 wv = *(const float4*)&wr[h];
            float4 xv = *(const float4*)&s_x[h];
            a0 += (double)xv.x * (double)wv.x;
            a1 += (double)xv.y * (double)wv.y;
            a2 += (double)xv.z * (double)wv.z;
            a3 += (double)xv.w * (double)wv.w;
        }
        dv = ((a0 + a1) + (a2 + a3)) + (double)b_enc[di];
    }
    __syncthreads();
    if (tid < RECOMP) { s_dv[tid] = (tid < T) ? dv : -1e300; s_di[tid] = di; }

    // bitonic sort 128 on f64 values (desc, tie idx asc)
    for (int k = 2; k <= RECOMP; k <<= 1) {
        for (int j = k >> 1; j > 0; j >>= 1) {
            __syncthreads();
            if (tid < RECOMP / 2) {
                int p = tid;
                int i1 = (p / j) * 2 * j + (p % j);
                int i2 = i1 + j;
                bool up = ((i1 & k) == 0);
                double v1 = s_dv[i1], v2 = s_dv[i2];
                int  d1 = s_di[i1],  d2 = s_di[i2];
                bool before12 = (v1 > v2) || (v1 == v2 && d1 < d2);
                bool before21 = (v2 > v1) || (v2 == v1 && d2 < d1);
                bool sw = up ? before21 : before12;
                if (sw) { s_dv[i1] = v2; s_dv[i2] = v1; s_di[i1] = d2; s_di[i2] = d1; }
            }
        }
    }
    __syncthreads();
    if (tid < K_TOP) {
        double v = s_dv[tid];
        out_vals[b * K_TOP + tid] = (float)(v > 0.0 ? v : 0.0);   // relu AFTER top-k
        out_idx[b * K_TOP + tid]  = (float)s_di[tid];
    }
}

// ---------------- Kernel 5: decode  x_hat_t[h][b] = sum_j vals[b][j]*Wdec[h][idx[b][j]] + pre_bias[h]
__global__ void __launch_bounds__(64) decode_kernel(
        const float* __restrict__ out_vals,  // [B][64]
        const float* __restrict__ out_idx,   // [B][64] (float)
        const float* __restrict__ Wdec,      // [H][D]
        const float* __restrict__ pre_bias,
        float* __restrict__ x_hat_t) {       // [H][B] in ws
    __shared__ float2 s_vi[64 * 64];         // 32 KB: [j][lane] = (val, byte_off_as_float)
    const int lane = threadIdx.x;
    const int s0 = (blockIdx.x >> 3) & 15;

    for (int i = lane; i < 64 * 64; i += 64) {
        int j = i >> 6, bb = i & 63;
        int b = s0 * 64 + bb;
        float v = out_vals[b * K_TOP + j];
        int id = (int)out_idx[b * K_TOP + j];
        s_vi[i] = make_float2(v, __int_as_float(id << 2));
    }
    __syncthreads();

    const int b = s0 * 64 + lane;
    for (int wi = blockIdx.x; wi < H_DIM * 16; wi += 1280) {
        const int h = (wi & 7) + ((wi >> 7) << 3);
        const char* wr = (const char*)(Wdec + (size_t)h * D_DIM);
        float acc = 0.0f;
        #pragma unroll 8
        for (int j = 0; j < K_TOP; j++) {
            float2 vi = s_vi[j * 64 + lane];
            acc = fmaf(vi.x, *(const float*)(wr + __float_as_int(vi.y)), acc);
        }
        x_hat_t[(size_t)h * B_DIM + b] = acc + pre_bias[h];
    }
}

// ---------------- Kernel 6: transpose x_hat_t [H][B] -> x_hat [B][H] ----------------
__global__ void __launch_bounds__(256) transpose_kernel(const float* __restrict__ xt,
                                                        float* __restrict__ x_hat) {
    __shared__ float tile[64][65];
    const int hb = blockIdx.x * 64;          // grid.x = H/64 = 64
    const int bb = blockIdx.y * 64;          // grid.y = B/64 = 16
    const int tc = threadIdx.x & 63, tr = threadIdx.x >> 6;
    #pragma unroll
    for (int r = tr; r < 64; r += 4)
        tile[r][tc] = xt[(size_t)(hb + r) * B_DIM + bb + tc];
    __syncthreads();
    #pragma unroll
    for (int r = tr; r < 64; r += 4)
        x_hat[(size_t)(bb + r) * H_DIM + hb + tc] = tile[tc][r];
}

// ---------------- launch ----------------
extern "C" void kernel_launch(void* const* d_in, const int* in_sizes, int n_in,
                              void* d_out, int out_size, void* d_ws, size_t ws_size,
                              hipStream_t stream) {
    const float* x        = (const float*)d_in[0];
    const float* W_enc    = (const float*)d_in[1];
    const float* b_enc    = (const float*)d_in[2];
    const float* W_dec    = (const float*)d_in[3];
    const float* pre_bias = (const float*)d_in[4];

    float* out = (float*)d_out;
    float* x_hat    = out;                                   // B*H
    float* top_vals = out + (size_t)B_DIM * H_DIM;           // B*K
    float* top_idx  = top_vals + (size_t)B_DIM * K_TOP;      // B*K (as float)
    float* pre_act  = top_idx + (size_t)B_DIM * K_TOP;       // B*D

    // workspace layout
    unsigned short* xc = (unsigned short*)d_ws;                               // 8 MB
    int*   cidx  = (int*)((char*)d_ws + (size_t)B_DIM * H_DIM * 2);           // 2 MB
    float* cval  = (float*)((char*)cidx + (size_t)B_DIM * CAND_CAP * 4);      // 2 MB
    int*   cnt   = (int*)((char*)cval + (size_t)B_DIM * CAND_CAP * 4);        // 4 KB
    float* xhatt = (float*)((char*)cnt + 4096);                               // 16 MB [H][B]

    hipMemsetAsync(cnt, 0, B_DIM * sizeof(int), stream);

    convert_x_kernel<<<(B_DIM * H_DIM / 4) / 256, 256, 0, stream>>>(x, pre_bias, xc);

    dim3 ggrid(B_DIM / G_BM, D_DIM / G_BN);   // m fast
    gemm_enc_kernel<<<ggrid, 256, 0, stream>>>(xc, W_enc, b_enc, pre_act);

    collect_kernel<<<(B_DIM * (D_DIM / 4)) / 256, 256, 0, stream>>>(pre_act, cnt, cidx, cval);

    select_topk_kernel<<<B_DIM, 256, 0, stream>>>(x, pre_bias, W_enc, b_enc, cnt, cidx, cval,
                                                  top_vals, top_idx);

    decode_kernel<<<1280, 64, 0, stream>>>(top_vals, top_idx, W_dec, pre_bias, xhatt);

    dim3 tgrid(H_DIM / 64, B_DIM / 64);
    transpose_kernel<<<tgrid, 256, 0, stream>>>(xhatt, x_hat);
}

// Round 6
// 3000.124 us; speedup vs baseline: 1.2273x; 1.2273x over previous
//
#include <hip/hip_runtime.h>
#include <hip/hip_bf16.h>
#include <cstdint>
#include <cstddef>
#include <math.h>

#define B_DIM 1024
#define H_DIM 4096
#define D_DIM 65536
#define K_TOP 64
#define CAND_CAP 512
#define RECOMP 128
#define COLLECT_THRESH 2.8f

typedef float f32x4 __attribute__((ext_vector_type(4)));
typedef __bf16 bf16x8 __attribute__((ext_vector_type(8)));
typedef unsigned short u16x8 __attribute__((ext_vector_type(8)));

__device__ inline unsigned short f2bf(float f) {
    unsigned int u = __float_as_uint(f);
    unsigned int r = u + 0x7FFFu + ((u >> 16) & 1u);   // RNE
    return (unsigned short)(r >> 16);
}

// ---------------- Kernel 0: W_enc f32 -> bf16 (one pass) ----------------
__global__ void convert_w_kernel(const float* __restrict__ Wenc,
                                 unsigned short* __restrict__ wb) {
    size_t i = (size_t)blockIdx.x * blockDim.x + threadIdx.x;   // octet index, D*H/8
    const float* src = &Wenc[i * 8];
    float4 f0 = *(const float4*)src;
    float4 f1 = *(const float4*)(src + 4);
    u16x8 o;
    o[0] = f2bf(f0.x); o[1] = f2bf(f0.y); o[2] = f2bf(f0.z); o[3] = f2bf(f0.w);
    o[4] = f2bf(f1.x); o[5] = f2bf(f1.y); o[6] = f2bf(f1.z); o[7] = f2bf(f1.w);
    *(u16x8*)&wb[i * 8] = o;
}

// ---------------- Kernel 1: x_centered -> bf16 ----------------
__global__ void convert_x_kernel(const float* __restrict__ x,
                                 const float* __restrict__ pre_bias,
                                 unsigned short* __restrict__ xc) {
    int i = blockIdx.x * blockDim.x + threadIdx.x;      // quad index, total B*H/4
    float4 v = *(const float4*)&x[(size_t)i * 4];
    int h = (i * 4) & (H_DIM - 1);
    float4 pb = *(const float4*)&pre_bias[h];
    ushort4 o;
    o.x = f2bf(v.x - pb.x);
    o.y = f2bf(v.y - pb.y);
    o.z = f2bf(v.z - pb.z);
    o.w = f2bf(v.w - pb.w);
    *(ushort4*)&xc[(size_t)i * 4] = o;
}

// ---------------- Kernel 2 (main): all-bf16 MFMA GEMM, high-TLP ----------------
// BM=BN=128, BK=64, 4 waves (2x2), wave tile 64x64 -> acc 64 VGPR -> 4 waves/SIMD.
// Both operands via global_load_lds w16, linear LDS dest + pre-swizzled source,
// XOR slot^(row&7) swizzle on the read (round-5-verified pattern).
#define N_BM 128
#define N_BN 128
#define N_BK 64

__global__ void __launch_bounds__(256, 4) gemm_enc_bf16_kernel(
        const unsigned short* __restrict__ A,    // xc bf16 [B_DIM][H_DIM]
        const unsigned short* __restrict__ Wb,   // W_enc bf16 [D_DIM][H_DIM]
        const float* __restrict__ b_enc,
        float* __restrict__ pre_act) {
    __shared__ __align__(16) unsigned short sA[N_BM * N_BK];
    __shared__ __align__(16) unsigned short sB[N_BN * N_BK];

    const int tid = threadIdx.x;
    const int w = tid >> 6;
    const int l = tid & 63;
    const int bid = blockIdx.x;
    // XCD-chunked: xcd = bid&7 owns n-chunk [xcd*64, xcd*64+64); m cycles fastest
    const int m0 = (((bid >> 3) & 7)) * N_BM;
    const int n0 = ((bid & 7) * 64 + (bid >> 6)) * N_BN;
    const int wm = w >> 1, wn = w & 1;
    const int lrow8 = l >> 3, lseg = l & 7;
    const int sw_seg = lseg ^ lrow8;          // pre-swizzled source slot

    f32x4 acc[4][4] = {};

    for (int k0 = 0; k0 < H_DIM; k0 += N_BK) {
        // stage A: wave w fills rows [w*32, w*32+32), 4 issues x 8 rows (1KB linear)
        #pragma unroll
        for (int i = 0; i < 4; i++) {
            int rbase = w * 32 + i * 8;
            const unsigned short* src = &A[(size_t)(m0 + rbase + lrow8) * H_DIM + k0 + sw_seg * 8];
            __builtin_amdgcn_global_load_lds(
                (const __attribute__((address_space(1))) unsigned int*)src,
                (__attribute__((address_space(3))) unsigned int*)&sA[rbase * N_BK],
                16, 0, 0);
        }
        // stage B: same pattern from bf16 W_enc
        #pragma unroll
        for (int i = 0; i < 4; i++) {
            int rbase = w * 32 + i * 8;
            const unsigned short* src = &Wb[(size_t)(n0 + rbase + lrow8) * H_DIM + k0 + sw_seg * 8];
            __builtin_amdgcn_global_load_lds(
                (const __attribute__((address_space(1))) unsigned int*)src,
                (__attribute__((address_space(3))) unsigned int*)&sB[rbase * N_BK],
                16, 0, 0);
        }
        __syncthreads();

        #pragma unroll
        for (int ks = 0; ks < 2; ks++) {
            const int slot = ks * 4 + (l >> 4);
            const int rslot = (slot ^ (l & 7)) * 8;   // read-side swizzle (row&7 == l&7)
            bf16x8 bfr[4];
            #pragma unroll
            for (int nj = 0; nj < 4; nj++) {
                int r = wn * 64 + nj * 16 + (l & 15);
                bfr[nj] = *(bf16x8*)&sB[r * N_BK + rslot];
            }
            #pragma unroll
            for (int mi = 0; mi < 4; mi++) {
                int r = wm * 64 + mi * 16 + (l & 15);
                bf16x8 afr = *(bf16x8*)&sA[r * N_BK + rslot];
                #pragma unroll
                for (int nj = 0; nj < 4; nj++)
                    acc[mi][nj] = __builtin_amdgcn_mfma_f32_16x16x32_bf16(afr, bfr[nj], acc[mi][nj], 0, 0, 0);
            }
        }
        __syncthreads();
    }

    const int lc = l & 15, lr4 = (l >> 4) * 4;
    #pragma unroll
    for (int nj = 0; nj < 4; nj++) {
        int col = n0 + wn * 64 + nj * 16 + lc;
        float bias = b_enc[col];
        #pragma unroll
        for (int mi = 0; mi < 4; mi++) {
            int row = m0 + wm * 64 + mi * 16 + lr4;
            #pragma unroll
            for (int e = 0; e < 4; e++) {
                pre_act[(size_t)(row + e) * D_DIM + col] = acc[mi][nj][e] + bias;
            }
        }
    }
}

// ---------------- Kernel 2 (fallback, ws too small): round-5 GEMM ----------------
#define G_BM 256
#define G_BN 128
#define G_BK 64

__global__ void __launch_bounds__(256) gemm_enc_kernel(
        const unsigned short* __restrict__ A,
        const float* __restrict__ Wenc,
        const float* __restrict__ b_enc,
        float* __restrict__ pre_act) {
    __shared__ __align__(16) unsigned short sA[G_BM * G_BK];
    __shared__ __align__(16) unsigned short sB[G_BN * G_BK];

    const int tid = threadIdx.x;
    const int w = tid >> 6;
    const int l = tid & 63;
    const int m0 = blockIdx.x * G_BM;
    const int n0 = blockIdx.y * G_BN;
    const int wm = w >> 1, wn = w & 1;
    const int lrow8 = l >> 3, lseg = l & 7;
    const int sw_seg = lseg ^ lrow8;

    f32x4 acc[8][4] = {};

    for (int k0 = 0; k0 < H_DIM; k0 += G_BK) {
        #pragma unroll
        for (int i = 0; i < 8; i++) {
            int row = w * 64 + i * 8 + lrow8;
            const unsigned short* src = &A[(size_t)(m0 + row) * H_DIM + k0 + sw_seg * 8];
            __builtin_amdgcn_global_load_lds(
                (const __attribute__((address_space(1))) unsigned int*)src,
                (__attribute__((address_space(3))) unsigned int*)&sA[(w * 64 + i * 8) * G_BK],
                16, 0, 0);
        }
        #pragma unroll
        for (int i = 0; i < 4; i++) {
            int row = w * 32 + i * 8 + lrow8;
            const float* src = &Wenc[(size_t)(n0 + row) * H_DIM + k0 + lseg * 8];
            float4 f0 = *(const float4*)src;
            float4 f1 = *(const float4*)(src + 4);
            u16x8 o;
            o[0] = f2bf(f0.x); o[1] = f2bf(f0.y); o[2] = f2bf(f0.z); o[3] = f2bf(f0.w);
            o[4] = f2bf(f1.x); o[5] = f2bf(f1.y); o[6] = f2bf(f1.z); o[7] = f2bf(f1.w);
            *(u16x8*)&sB[row * G_BK + sw_seg * 8] = o;
        }
        __syncthreads();

        #pragma unroll
        for (int ks = 0; ks < 2; ks++) {
            const int slot = ks * 4 + (l >> 4);
            const int rslot = (slot ^ (l & 7)) * 8;
            bf16x8 bfr[4];
            #pragma unroll
            for (int nj = 0; nj < 4; nj++) {
                int r = wn * 64 + nj * 16 + (l & 15);
                bfr[nj] = *(bf16x8*)&sB[r * G_BK + rslot];
            }
            #pragma unroll
            for (int mi = 0; mi < 8; mi++) {
                int r = wm * 128 + mi * 16 + (l & 15);
                bf16x8 afr = *(bf16x8*)&sA[r * G_BK + rslot];
                #pragma unroll
                for (int nj = 0; nj < 4; nj++)
                    acc[mi][nj] = __builtin_amdgcn_mfma_f32_16x16x32_bf16(afr, bfr[nj], acc[mi][nj], 0, 0, 0);
            }
        }
        __syncthreads();
    }

    const int lc = l & 15, lr4 = (l >> 4) * 4;
    #pragma unroll
    for (int nj = 0; nj < 4; nj++) {
        int col = n0 + wn * 64 + nj * 16 + lc;
        float bias = b_enc[col];
        #pragma unroll
        for (int mi = 0; mi < 8; mi++) {
            int row = m0 + wm * 128 + mi * 16 + lr4;
            #pragma unroll
            for (int e = 0; e < 4; e++) {
                pre_act[(size_t)(row + e) * D_DIM + col] = acc[mi][nj][e] + bias;
            }
        }
    }
}

// ---------------- Kernel 3: collect candidates (pre_act > THRESH) ----------------
__global__ void collect_kernel(const float* __restrict__ pre_act,
                               int* __restrict__ cnt,
                               int* __restrict__ cidx,
                               float* __restrict__ cval) {
    int i = blockIdx.x * blockDim.x + threadIdx.x;
    float4 v = *(const float4*)&pre_act[(size_t)i * 4];
    float fv[4] = {v.x, v.y, v.z, v.w};
    int base = i * 4;
    #pragma unroll
    for (int e = 0; e < 4; e++) {
        if (fv[e] > COLLECT_THRESH) {
            int idx = base + e;
            int b = idx >> 16;
            int d = idx & (D_DIM - 1);
            int p = atomicAdd(&cnt[b], 1);
            if (p < CAND_CAP) {
                cidx[b * CAND_CAP + p] = d;
                cval[b * CAND_CAP + p] = fv[e];
            }
        }
    }
}

// ---------------- Kernel 4: approx sort -> f64 recompute (WITH bias) -> exact top-64 ----------------
__global__ void __launch_bounds__(256) select_topk_kernel(
        const float* __restrict__ x, const float* __restrict__ pre_bias,
        const float* __restrict__ Wenc, const float* __restrict__ b_enc,
        const int* __restrict__ cnt, const int* __restrict__ cidx, const float* __restrict__ cval,
        float* __restrict__ out_vals, float* __restrict__ out_idx) {
    __shared__ float s_val[CAND_CAP];
    __shared__ int   s_idx[CAND_CAP];
    __shared__ __align__(16) float s_x[H_DIM];
    __shared__ double s_dv[RECOMP];
    __shared__ int    s_di[RECOMP];

    const int b = blockIdx.x;
    const int tid = threadIdx.x;

    for (int i = tid; i < H_DIM / 4; i += 256) {
        float4 xv = *(const float4*)&x[(size_t)b * H_DIM + i * 4];
        float4 pb = *(const float4*)&pre_bias[i * 4];
        xv.x -= pb.x; xv.y -= pb.y; xv.z -= pb.z; xv.w -= pb.w;
        *(float4*)&s_x[i * 4] = xv;
    }
    const int n = min(cnt[b], CAND_CAP);
    for (int i = tid; i < CAND_CAP; i += 256) {
        if (i < n) { s_val[i] = cval[b * CAND_CAP + i]; s_idx[i] = cidx[b * CAND_CAP + i]; }
        else       { s_val[i] = -1e30f;                 s_idx[i] = 0x7FFFFFFF; }
    }
    __syncthreads();

    for (int k = 2; k <= CAND_CAP; k <<= 1) {
        for (int j = k >> 1; j > 0; j >>= 1) {
            int p = tid;
            int i1 = (p / j) * 2 * j + (p % j);
            int i2 = i1 + j;
            bool up = ((i1 & k) == 0);
            float v1 = s_val[i1], v2 = s_val[i2];
            int  d1 = s_idx[i1],  d2 = s_idx[i2];
            bool before12 = (v1 > v2) || (v1 == v2 && d1 < d2);
            bool before21 = (v2 > v1) || (v2 == v1 && d2 < d1);
            bool sw = up ? before21 : before12;
            __syncthreads();
            if (sw) { s_val[i1] = v2; s_val[i2] = v1; s_idx[i1] = d2; s_idx[i2] = d1; }
            __syncthreads();
        }
    }

    const int T = min(RECOMP, n);
    double dv = -1e300;
    int di = 0x7FFFFFFF;
    if (tid < T) {
        di = s_idx[tid];
        const float* wr = &Wenc[(size_t)di * H_DIM];
        double a0 = 0, a1 = 0, a2 = 0, a3 = 0;
        for (int h = 0; h < H_DIM; h += 4) {
            float4 wv = *(const float4*)&wr[h];
            float4 xv = *(const float4*)&s_x[h];
            a0 += (double)xv.x * (double)wv.x;
            a1 += (double)xv.y * (double)wv.y;
            a2 += (double)xv.z * (double)wv.z;
            a3 += (double)xv.w * (double)wv.w;
        }
        dv = ((a0 + a1) + (a2 + a3)) + (double)b_enc[di];
    }
    __syncthreads();
    if (tid < RECOMP) { s_dv[tid] = (tid < T) ? dv : -1e300; s_di[tid] = di; }

    for (int k = 2; k <= RECOMP; k <<= 1) {
        for (int j = k >> 1; j > 0; j >>= 1) {
            __syncthreads();
            if (tid < RECOMP / 2) {
                int p = tid;
                int i1 = (p / j) * 2 * j + (p % j);
                int i2 = i1 + j;
                bool up = ((i1 & k) == 0);
                double v1 = s_dv[i1], v2 = s_dv[i2];
                int  d1 = s_di[i1],  d2 = s_di[i2];
                bool before12 = (v1 > v2) || (v1 == v2 && d1 < d2);
                bool before21 = (v2 > v1) || (v2 == v1 && d2 < d1);
                bool sw = up ? before21 : before12;
                if (sw) { s_dv[i1] = v2; s_dv[i2] = v1; s_di[i1] = d2; s_di[i2] = d1; }
            }
        }
    }
    __syncthreads();
    if (tid < K_TOP) {
        double v = s_dv[tid];
        out_vals[b * K_TOP + tid] = (float)(v > 0.0 ? v : 0.0);
        out_idx[b * K_TOP + tid]  = (float)s_di[tid];
    }
}

// ---------------- Kernel 5: decode ----------------
__global__ void __launch_bounds__(64) decode_kernel(
        const float* __restrict__ out_vals,
        const float* __restrict__ out_idx,
        const float* __restrict__ Wdec,
        const float* __restrict__ pre_bias,
        float* __restrict__ x_hat_t) {
    __shared__ float2 s_vi[64 * 64];
    const int lane = threadIdx.x;
    const int s0 = (blockIdx.x >> 3) & 15;

    for (int i = lane; i < 64 * 64; i += 64) {
        int j = i >> 6, bb = i & 63;
        int b = s0 * 64 + bb;
        float v = out_vals[b * K_TOP + j];
        int id = (int)out_idx[b * K_TOP + j];
        s_vi[i] = make_float2(v, __int_as_float(id << 2));
    }
    __syncthreads();

    const int b = s0 * 64 + lane;
    for (int wi = blockIdx.x; wi < H_DIM * 16; wi += 1280) {
        const int h = (wi & 7) + ((wi >> 7) << 3);
        const char* wr = (const char*)(Wdec + (size_t)h * D_DIM);
        float acc = 0.0f;
        #pragma unroll 8
        for (int j = 0; j < K_TOP; j++) {
            float2 vi = s_vi[j * 64 + lane];
            acc = fmaf(vi.x, *(const float*)(wr + __float_as_int(vi.y)), acc);
        }
        x_hat_t[(size_t)h * B_DIM + b] = acc + pre_bias[h];
    }
}

// ---------------- Kernel 6: transpose ----------------
__global__ void __launch_bounds__(256) transpose_kernel(const float* __restrict__ xt,
                                                        float* __restrict__ x_hat) {
    __shared__ float tile[64][65];
    const int hb = blockIdx.x * 64;
    const int bb = blockIdx.y * 64;
    const int tc = threadIdx.x & 63, tr = threadIdx.x >> 6;
    #pragma unroll
    for (int r = tr; r < 64; r += 4)
        tile[r][tc] = xt[(size_t)(hb + r) * B_DIM + bb + tc];
    __syncthreads();
    #pragma unroll
    for (int r = tr; r < 64; r += 4)
        x_hat[(size_t)(bb + r) * H_DIM + hb + tc] = tile[tc][r];
}

// ---------------- launch ----------------
extern "C" void kernel_launch(void* const* d_in, const int* in_sizes, int n_in,
                              void* d_out, int out_size, void* d_ws, size_t ws_size,
                              hipStream_t stream) {
    const float* x        = (const float*)d_in[0];
    const float* W_enc    = (const float*)d_in[1];
    const float* b_enc    = (const float*)d_in[2];
    const float* W_dec    = (const float*)d_in[3];
    const float* pre_bias = (const float*)d_in[4];

    float* out = (float*)d_out;
    float* x_hat    = out;
    float* top_vals = out + (size_t)B_DIM * H_DIM;
    float* top_idx  = top_vals + (size_t)B_DIM * K_TOP;
    float* pre_act  = top_idx + (size_t)B_DIM * K_TOP;

    // workspace layout
    unsigned short* xc = (unsigned short*)d_ws;                               // [0, 8MB)
    int*   cidx  = (int*)((char*)d_ws + (size_t)B_DIM * H_DIM * 2);           // [8, 10MB)
    float* cval  = (float*)((char*)cidx + (size_t)B_DIM * CAND_CAP * 4);      // [10, 12MB)
    int*   cnt   = (int*)((char*)cval + (size_t)B_DIM * CAND_CAP * 4);        // [12MB, +4KB)
    float* xhatt = (float*)((char*)cnt + 4096);                               // [~12MB, ~28MB)
    const size_t WENC_OFF = 32ull << 20;                                      // 32 MB aligned
    unsigned short* wenc_bf = (unsigned short*)((char*)d_ws + WENC_OFF);      // 512 MB
    const bool big_ws = ws_size >= WENC_OFF + ((size_t)D_DIM * H_DIM * 2) + (1 << 20);

    hipMemsetAsync(cnt, 0, B_DIM * sizeof(int), stream);

    convert_x_kernel<<<(B_DIM * H_DIM / 4) / 256, 256, 0, stream>>>(x, pre_bias, xc);

    if (big_ws) {
        convert_w_kernel<<<((size_t)D_DIM * H_DIM / 8) / 256, 256, 0, stream>>>(W_enc, wenc_bf);
        gemm_enc_bf16_kernel<<<(B_DIM / N_BM) * (D_DIM / N_BN), 256, 0, stream>>>(
            xc, wenc_bf, b_enc, pre_act);
    } else {
        dim3 ggrid(B_DIM / G_BM, D_DIM / G_BN);
        gemm_enc_kernel<<<ggrid, 256, 0, stream>>>(xc, W_enc, b_enc, pre_act);
    }

    collect_kernel<<<(B_DIM * (D_DIM / 4)) / 256, 256, 0, stream>>>(pre_act, cnt, cidx, cval);

    select_topk_kernel<<<B_DIM, 256, 0, stream>>>(x, pre_bias, W_enc, b_enc, cnt, cidx, cval,
                                                  top_vals, top_idx);

    decode_kernel<<<1280, 64, 0, stream>>>(top_vals, top_idx, W_dec, pre_bias, xhatt);

    dim3 tgrid(H_DIM / 64, B_DIM / 64);
    transpose_kernel<<<tgrid, 256, 0, stream>>>(xhatt, x_hat);
}

// Round 7
// 2267.125 us; speedup vs baseline: 1.6241x; 1.3233x over previous
//
#include <hip/hip_runtime.h>
#include <hip/hip_bf16.h>
#include <cstdint>
#include <cstddef>
#include <math.h>

#define B_DIM 1024
#define H_DIM 4096
#define D_DIM 65536
#define K_TOP 64
#define CAND_CAP 512
#define RECOMP 128
#define COLLECT_THRESH 2.8f

typedef float f32x4 __attribute__((ext_vector_type(4)));
typedef __bf16 bf16x8 __attribute__((ext_vector_type(8)));
typedef unsigned short u16x8 __attribute__((ext_vector_type(8)));

__device__ inline unsigned short f2bf(float f) {
    unsigned int u = __float_as_uint(f);
    unsigned int r = u + 0x7FFFu + ((u >> 16) & 1u);   // RNE
    return (unsigned short)(r >> 16);
}
__device__ inline float bf2f(unsigned short s) {
    return __uint_as_float(((unsigned int)s) << 16);
}

// ---------------- Kernel 0: W_enc f32 -> bf16 (one pass) ----------------
__global__ void convert_w_kernel(const float* __restrict__ Wenc,
                                 unsigned short* __restrict__ wb) {
    size_t i = (size_t)blockIdx.x * blockDim.x + threadIdx.x;   // octet index, D*H/8
    const float* src = &Wenc[i * 8];
    float4 f0 = *(const float4*)src;
    float4 f1 = *(const float4*)(src + 4);
    u16x8 o;
    o[0] = f2bf(f0.x); o[1] = f2bf(f0.y); o[2] = f2bf(f0.z); o[3] = f2bf(f0.w);
    o[4] = f2bf(f1.x); o[5] = f2bf(f1.y); o[6] = f2bf(f1.z); o[7] = f2bf(f1.w);
    *(u16x8*)&wb[i * 8] = o;
}

// ---------------- Kernel 1: x_centered -> bf16 ----------------
__global__ void convert_x_kernel(const float* __restrict__ x,
                                 const float* __restrict__ pre_bias,
                                 unsigned short* __restrict__ xc) {
    int i = blockIdx.x * blockDim.x + threadIdx.x;      // quad index, total B*H/4
    float4 v = *(const float4*)&x[(size_t)i * 4];
    int h = (i * 4) & (H_DIM - 1);
    float4 pb = *(const float4*)&pre_bias[h];
    ushort4 o;
    o.x = f2bf(v.x - pb.x);
    o.y = f2bf(v.y - pb.y);
    o.z = f2bf(v.z - pb.z);
    o.w = f2bf(v.w - pb.w);
    *(ushort4*)&xc[(size_t)i * 4] = o;
}

// ---------------- Kernel 2 (main): all-bf16 MFMA GEMM, high-TLP ----------------
#define N_BM 128
#define N_BN 128
#define N_BK 64

__global__ void __launch_bounds__(256, 4) gemm_enc_bf16_kernel(
        const unsigned short* __restrict__ A,    // xc bf16 [B_DIM][H_DIM]
        const unsigned short* __restrict__ Wb,   // W_enc bf16 [D_DIM][H_DIM]
        const float* __restrict__ b_enc,
        float* __restrict__ pre_act) {
    __shared__ __align__(16) unsigned short sA[N_BM * N_BK];
    __shared__ __align__(16) unsigned short sB[N_BN * N_BK];

    const int tid = threadIdx.x;
    const int w = tid >> 6;
    const int l = tid & 63;
    const int bid = blockIdx.x;
    const int m0 = (((bid >> 3) & 7)) * N_BM;
    const int n0 = ((bid & 7) * 64 + (bid >> 6)) * N_BN;
    const int wm = w >> 1, wn = w & 1;
    const int lrow8 = l >> 3, lseg = l & 7;
    const int sw_seg = lseg ^ lrow8;          // pre-swizzled source slot

    f32x4 acc[4][4] = {};

    for (int k0 = 0; k0 < H_DIM; k0 += N_BK) {
        #pragma unroll
        for (int i = 0; i < 4; i++) {
            int rbase = w * 32 + i * 8;
            const unsigned short* src = &A[(size_t)(m0 + rbase + lrow8) * H_DIM + k0 + sw_seg * 8];
            __builtin_amdgcn_global_load_lds(
                (const __attribute__((address_space(1))) unsigned int*)src,
                (__attribute__((address_space(3))) unsigned int*)&sA[rbase * N_BK],
                16, 0, 0);
        }
        #pragma unroll
        for (int i = 0; i < 4; i++) {
            int rbase = w * 32 + i * 8;
            const unsigned short* src = &Wb[(size_t)(n0 + rbase + lrow8) * H_DIM + k0 + sw_seg * 8];
            __builtin_amdgcn_global_load_lds(
                (const __attribute__((address_space(1))) unsigned int*)src,
                (__attribute__((address_space(3))) unsigned int*)&sB[rbase * N_BK],
                16, 0, 0);
        }
        __syncthreads();

        #pragma unroll
        for (int ks = 0; ks < 2; ks++) {
            const int slot = ks * 4 + (l >> 4);
            const int rslot = (slot ^ (l & 7)) * 8;
            bf16x8 bfr[4];
            #pragma unroll
            for (int nj = 0; nj < 4; nj++) {
                int r = wn * 64 + nj * 16 + (l & 15);
                bfr[nj] = *(bf16x8*)&sB[r * N_BK + rslot];
            }
            #pragma unroll
            for (int mi = 0; mi < 4; mi++) {
                int r = wm * 64 + mi * 16 + (l & 15);
                bf16x8 afr = *(bf16x8*)&sA[r * N_BK + rslot];
                #pragma unroll
                for (int nj = 0; nj < 4; nj++)
                    acc[mi][nj] = __builtin_amdgcn_mfma_f32_16x16x32_bf16(afr, bfr[nj], acc[mi][nj], 0, 0, 0);
            }
        }
        __syncthreads();
    }

    const int lc = l & 15, lr4 = (l >> 4) * 4;
    #pragma unroll
    for (int nj = 0; nj < 4; nj++) {
        int col = n0 + wn * 64 + nj * 16 + lc;
        float bias = b_enc[col];
        #pragma unroll
        for (int mi = 0; mi < 4; mi++) {
            int row = m0 + wm * 64 + mi * 16 + lr4;
            #pragma unroll
            for (int e = 0; e < 4; e++) {
                pre_act[(size_t)(row + e) * D_DIM + col] = acc[mi][nj][e] + bias;
            }
        }
    }
}

// ---------------- Kernel 2 (fallback, ws too small): round-5 GEMM ----------------
#define G_BM 256
#define G_BN 128
#define G_BK 64

__global__ void __launch_bounds__(256) gemm_enc_kernel(
        const unsigned short* __restrict__ A,
        const float* __restrict__ Wenc,
        const float* __restrict__ b_enc,
        float* __restrict__ pre_act) {
    __shared__ __align__(16) unsigned short sA[G_BM * G_BK];
    __shared__ __align__(16) unsigned short sB[G_BN * G_BK];

    const int tid = threadIdx.x;
    const int w = tid >> 6;
    const int l = tid & 63;
    const int m0 = blockIdx.x * G_BM;
    const int n0 = blockIdx.y * G_BN;
    const int wm = w >> 1, wn = w & 1;
    const int lrow8 = l >> 3, lseg = l & 7;
    const int sw_seg = lseg ^ lrow8;

    f32x4 acc[8][4] = {};

    for (int k0 = 0; k0 < H_DIM; k0 += G_BK) {
        #pragma unroll
        for (int i = 0; i < 8; i++) {
            int row = w * 64 + i * 8 + lrow8;
            const unsigned short* src = &A[(size_t)(m0 + row) * H_DIM + k0 + sw_seg * 8];
            __builtin_amdgcn_global_load_lds(
                (const __attribute__((address_space(1))) unsigned int*)src,
                (__attribute__((address_space(3))) unsigned int*)&sA[(w * 64 + i * 8) * G_BK],
                16, 0, 0);
        }
        #pragma unroll
        for (int i = 0; i < 4; i++) {
            int row = w * 32 + i * 8 + lrow8;
            const float* src = &Wenc[(size_t)(n0 + row) * H_DIM + k0 + lseg * 8];
            float4 f0 = *(const float4*)src;
            float4 f1 = *(const float4*)(src + 4);
            u16x8 o;
            o[0] = f2bf(f0.x); o[1] = f2bf(f0.y); o[2] = f2bf(f0.z); o[3] = f2bf(f0.w);
            o[4] = f2bf(f1.x); o[5] = f2bf(f1.y); o[6] = f2bf(f1.z); o[7] = f2bf(f1.w);
            *(u16x8*)&sB[row * G_BK + sw_seg * 8] = o;
        }
        __syncthreads();

        #pragma unroll
        for (int ks = 0; ks < 2; ks++) {
            const int slot = ks * 4 + (l >> 4);
            const int rslot = (slot ^ (l & 7)) * 8;
            bf16x8 bfr[4];
            #pragma unroll
            for (int nj = 0; nj < 4; nj++) {
                int r = wn * 64 + nj * 16 + (l & 15);
                bfr[nj] = *(bf16x8*)&sB[r * G_BK + rslot];
            }
            #pragma unroll
            for (int mi = 0; mi < 8; mi++) {
                int r = wm * 128 + mi * 16 + (l & 15);
                bf16x8 afr = *(bf16x8*)&sA[r * G_BK + rslot];
                #pragma unroll
                for (int nj = 0; nj < 4; nj++)
                    acc[mi][nj] = __builtin_amdgcn_mfma_f32_16x16x32_bf16(afr, bfr[nj], acc[mi][nj], 0, 0, 0);
            }
        }
        __syncthreads();
    }

    const int lc = l & 15, lr4 = (l >> 4) * 4;
    #pragma unroll
    for (int nj = 0; nj < 4; nj++) {
        int col = n0 + wn * 64 + nj * 16 + lc;
        float bias = b_enc[col];
        #pragma unroll
        for (int mi = 0; mi < 8; mi++) {
            int row = m0 + wm * 128 + mi * 16 + lr4;
            #pragma unroll
            for (int e = 0; e < 4; e++) {
                pre_act[(size_t)(row + e) * D_DIM + col] = acc[mi][nj][e] + bias;
            }
        }
    }
}

// ---------------- Kernel 3: collect candidates (pre_act > THRESH) ----------------
__global__ void collect_kernel(const float* __restrict__ pre_act,
                               int* __restrict__ cnt,
                               int* __restrict__ cidx,
                               float* __restrict__ cval) {
    int i = blockIdx.x * blockDim.x + threadIdx.x;
    float4 v = *(const float4*)&pre_act[(size_t)i * 4];
    float fv[4] = {v.x, v.y, v.z, v.w};
    int base = i * 4;
    #pragma unroll
    for (int e = 0; e < 4; e++) {
        if (fv[e] > COLLECT_THRESH) {
            int idx = base + e;
            int b = idx >> 16;
            int d = idx & (D_DIM - 1);
            int p = atomicAdd(&cnt[b], 1);
            if (p < CAND_CAP) {
                cidx[b * CAND_CAP + p] = d;
                cval[b * CAND_CAP + p] = fv[e];
            }
        }
    }
}

// ---------------- Kernel 4: approx sort -> f64 recompute (WITH bias) -> exact top-64 ----------------
__global__ void __launch_bounds__(256) select_topk_kernel(
        const float* __restrict__ x, const float* __restrict__ pre_bias,
        const float* __restrict__ Wenc, const float* __restrict__ b_enc,
        const int* __restrict__ cnt, const int* __restrict__ cidx, const float* __restrict__ cval,
        float* __restrict__ out_vals, float* __restrict__ out_idx) {
    __shared__ float s_val[CAND_CAP];
    __shared__ int   s_idx[CAND_CAP];
    __shared__ __align__(16) float s_x[H_DIM];
    __shared__ double s_dv[RECOMP];
    __shared__ int    s_di[RECOMP];

    const int b = blockIdx.x;
    const int tid = threadIdx.x;

    for (int i = tid; i < H_DIM / 4; i += 256) {
        float4 xv = *(const float4*)&x[(size_t)b * H_DIM + i * 4];
        float4 pb = *(const float4*)&pre_bias[i * 4];
        xv.x -= pb.x; xv.y -= pb.y; xv.z -= pb.z; xv.w -= pb.w;
        *(float4*)&s_x[i * 4] = xv;
    }
    const int n = min(cnt[b], CAND_CAP);
    for (int i = tid; i < CAND_CAP; i += 256) {
        if (i < n) { s_val[i] = cval[b * CAND_CAP + i]; s_idx[i] = cidx[b * CAND_CAP + i]; }
        else       { s_val[i] = -1e30f;                 s_idx[i] = 0x7FFFFFFF; }
    }
    __syncthreads();

    for (int k = 2; k <= CAND_CAP; k <<= 1) {
        for (int j = k >> 1; j > 0; j >>= 1) {
            int p = tid;
            int i1 = (p / j) * 2 * j + (p % j);
            int i2 = i1 + j;
            bool up = ((i1 & k) == 0);
            float v1 = s_val[i1], v2 = s_val[i2];
            int  d1 = s_idx[i1],  d2 = s_idx[i2];
            bool before12 = (v1 > v2) || (v1 == v2 && d1 < d2);
            bool before21 = (v2 > v1) || (v2 == v1 && d2 < d1);
            bool sw = up ? before21 : before12;
            __syncthreads();
            if (sw) { s_val[i1] = v2; s_val[i2] = v1; s_idx[i1] = d2; s_idx[i2] = d1; }
            __syncthreads();
        }
    }

    const int T = min(RECOMP, n);
    double dv = -1e300;
    int di = 0x7FFFFFFF;
    if (tid < T) {
        di = s_idx[tid];
        const float* wr = &Wenc[(size_t)di * H_DIM];
        double a0 = 0, a1 = 0, a2 = 0, a3 = 0;
        for (int h = 0; h < H_DIM; h += 4) {
            float4 wv = *(const float4*)&wr[h];
            float4 xv = *(const float4*)&s_x[h];
            a0 += (double)xv.x * (double)wv.x;
            a1 += (double)xv.y * (double)wv.y;
            a2 += (double)xv.z * (double)wv.z;
            a3 += (double)xv.w * (double)wv.w;
        }
        dv = ((a0 + a1) + (a2 + a3)) + (double)b_enc[di];
    }
    __syncthreads();
    if (tid < RECOMP) { s_dv[tid] = (tid < T) ? dv : -1e300; s_di[tid] = di; }

    for (int k = 2; k <= RECOMP; k <<= 1) {
        for (int j = k >> 1; j > 0; j >>= 1) {
            __syncthreads();
            if (tid < RECOMP / 2) {
                int p = tid;
                int i1 = (p / j) * 2 * j + (p % j);
                int i2 = i1 + j;
                bool up = ((i1 & k) == 0);
                double v1 = s_dv[i1], v2 = s_dv[i2];
                int  d1 = s_di[i1],  d2 = s_di[i2];
                bool before12 = (v1 > v2) || (v1 == v2 && d1 < d2);
                bool before21 = (v2 > v1) || (v2 == v1 && d2 < d1);
                bool sw = up ? before21 : before12;
                if (sw) { s_dv[i1] = v2; s_dv[i2] = v1; s_di[i1] = d2; s_di[i2] = d1; }
            }
        }
    }
    __syncthreads();
    if (tid < K_TOP) {
        double v = s_dv[tid];
        out_vals[b * K_TOP + tid] = (float)(v > 0.0 ? v : 0.0);
        out_idx[b * K_TOP + tid]  = (float)s_di[tid];
    }
}

// ---------------- Kernel 5a: W_dec [H][D] f32 -> W_dec^T [D][H] bf16 ----------------
// Classic 64x65-pad LDS tile. Reads 256B/instr; writes 128B/instr = full 64B lines.
__global__ void __launch_bounds__(256) transpose_wdec_kernel(
        const float* __restrict__ Wdec, unsigned short* __restrict__ WdecT) {
    __shared__ float tile[64][65];
    const int d0 = blockIdx.x * 64;          // grid.x = D/64 = 1024
    const int h0 = blockIdx.y * 64;          // grid.y = H/64 = 64
    const int tc = threadIdx.x & 63, tr = threadIdx.x >> 6;
    #pragma unroll
    for (int hh = tr; hh < 64; hh += 4)
        tile[hh][tc] = Wdec[(size_t)(h0 + hh) * D_DIM + d0 + tc];
    __syncthreads();
    #pragma unroll
    for (int dd = tr; dd < 64; dd += 4)
        WdecT[(size_t)(d0 + dd) * H_DIM + h0 + tc] = f2bf(tile[tc][dd]);
}

// ---------------- Kernel 5b: decode as scaled row-sum over W_dec^T ----------------
// x_hat[b][:] = sum_j val[b][j] * WdecT[idx[b][j]][:] + pre_bias
// One block per b; 64 contiguous 8KB row reads per block (streaming, ~512MB total).
__global__ void __launch_bounds__(256) decode_rows_kernel(
        const float* __restrict__ out_vals,   // [B][64]
        const float* __restrict__ out_idx,    // [B][64] (float)
        const unsigned short* __restrict__ WdecT,  // [D][H] bf16
        const float* __restrict__ pre_bias,
        float* __restrict__ x_hat) {          // [B][H]
    __shared__ float s_v[K_TOP];
    __shared__ int   s_d[K_TOP];
    const int b = blockIdx.x;
    const int t = threadIdx.x;

    if (t < K_TOP) {
        s_v[t] = out_vals[b * K_TOP + t];
        s_d[t] = (int)out_idx[b * K_TOP + t];
    }
    __syncthreads();

    float acc[16] = {};   // h = c*2048 + t*8 + e, c in {0,1}
    #pragma unroll 4
    for (int j = 0; j < K_TOP; j++) {
        float v = s_v[j];
        const unsigned short* wr = &WdecT[(size_t)s_d[j] * H_DIM];
        u16x8 w0 = *(const u16x8*)&wr[t * 8];
        u16x8 w1 = *(const u16x8*)&wr[2048 + t * 8];
        #pragma unroll
        for (int e = 0; e < 8; e++) {
            acc[e]     = fmaf(v, bf2f(w0[e]), acc[e]);
            acc[8 + e] = fmaf(v, bf2f(w1[e]), acc[8 + e]);
        }
    }
    #pragma unroll
    for (int c = 0; c < 2; c++) {
        int h = c * 2048 + t * 8;
        float4 pb0 = *(const float4*)&pre_bias[h];
        float4 pb1 = *(const float4*)&pre_bias[h + 4];
        float4 o0, o1;
        o0.x = acc[c*8+0] + pb0.x; o0.y = acc[c*8+1] + pb0.y;
        o0.z = acc[c*8+2] + pb0.z; o0.w = acc[c*8+3] + pb0.w;
        o1.x = acc[c*8+4] + pb1.x; o1.y = acc[c*8+5] + pb1.y;
        o1.z = acc[c*8+6] + pb1.z; o1.w = acc[c*8+7] + pb1.w;
        *(float4*)&x_hat[(size_t)b * H_DIM + h]     = o0;
        *(float4*)&x_hat[(size_t)b * H_DIM + h + 4] = o1;
    }
}

// ---------------- Fallback decode (ws too small): round-6 gather path ----------------
__global__ void __launch_bounds__(64) decode_kernel(
        const float* __restrict__ out_vals,
        const float* __restrict__ out_idx,
        const float* __restrict__ Wdec,
        const float* __restrict__ pre_bias,
        float* __restrict__ x_hat_t) {
    __shared__ float2 s_vi[64 * 64];
    const int lane = threadIdx.x;
    const int s0 = (blockIdx.x >> 3) & 15;

    for (int i = lane; i < 64 * 64; i += 64) {
        int j = i >> 6, bb = i & 63;
        int b = s0 * 64 + bb;
        float v = out_vals[b * K_TOP + j];
        int id = (int)out_idx[b * K_TOP + j];
        s_vi[i] = make_float2(v, __int_as_float(id << 2));
    }
    __syncthreads();

    const int b = s0 * 64 + lane;
    for (int wi = blockIdx.x; wi < H_DIM * 16; wi += 1280) {
        const int h = (wi & 7) + ((wi >> 7) << 3);
        const char* wr = (const char*)(Wdec + (size_t)h * D_DIM);
        float acc = 0.0f;
        #pragma unroll 8
        for (int j = 0; j < K_TOP; j++) {
            float2 vi = s_vi[j * 64 + lane];
            acc = fmaf(vi.x, *(const float*)(wr + __float_as_int(vi.y)), acc);
        }
        x_hat_t[(size_t)h * B_DIM + b] = acc + pre_bias[h];
    }
}

__global__ void __launch_bounds__(256) transpose_kernel(const float* __restrict__ xt,
                                                        float* __restrict__ x_hat) {
    __shared__ float tile[64][65];
    const int hb = blockIdx.x * 64;
    const int bb = blockIdx.y * 64;
    const int tc = threadIdx.x & 63, tr = threadIdx.x >> 6;
    #pragma unroll
    for (int r = tr; r < 64; r += 4)
        tile[r][tc] = xt[(size_t)(hb + r) * B_DIM + bb + tc];
    __syncthreads();
    #pragma unroll
    for (int r = tr; r < 64; r += 4)
        x_hat[(size_t)(bb + r) * H_DIM + hb + tc] = tile[tc][r];
}

// ---------------- launch ----------------
extern "C" void kernel_launch(void* const* d_in, const int* in_sizes, int n_in,
                              void* d_out, int out_size, void* d_ws, size_t ws_size,
                              hipStream_t stream) {
    const float* x        = (const float*)d_in[0];
    const float* W_enc    = (const float*)d_in[1];
    const float* b_enc    = (const float*)d_in[2];
    const float* W_dec    = (const float*)d_in[3];
    const float* pre_bias = (const float*)d_in[4];

    float* out = (float*)d_out;
    float* x_hat    = out;
    float* top_vals = out + (size_t)B_DIM * H_DIM;
    float* top_idx  = top_vals + (size_t)B_DIM * K_TOP;
    float* pre_act  = top_idx + (size_t)B_DIM * K_TOP;

    // workspace layout
    unsigned short* xc = (unsigned short*)d_ws;                               // [0, 8MB)
    int*   cidx  = (int*)((char*)d_ws + (size_t)B_DIM * H_DIM * 2);           // [8, 10MB)
    float* cval  = (float*)((char*)cidx + (size_t)B_DIM * CAND_CAP * 4);      // [10, 12MB)
    int*   cnt   = (int*)((char*)cval + (size_t)B_DIM * CAND_CAP * 4);        // [12MB, +4KB)
    float* xhatt = (float*)((char*)cnt + 4096);                               // [~12, ~28MB) (fallback only)
    const size_t WENC_OFF = 32ull << 20;                                      // 32 MB aligned
    unsigned short* wenc_bf = (unsigned short*)((char*)d_ws + WENC_OFF);      // 512 MB
    // W_dec^T bf16 overlays the wenc_bf region (used strictly after the GEMM)
    unsigned short* wdecT = wenc_bf;
    const bool big_ws = ws_size >= WENC_OFF + ((size_t)D_DIM * H_DIM * 2) + (1 << 20);

    hipMemsetAsync(cnt, 0, B_DIM * sizeof(int), stream);

    convert_x_kernel<<<(B_DIM * H_DIM / 4) / 256, 256, 0, stream>>>(x, pre_bias, xc);

    if (big_ws) {
        convert_w_kernel<<<((size_t)D_DIM * H_DIM / 8) / 256, 256, 0, stream>>>(W_enc, wenc_bf);
        gemm_enc_bf16_kernel<<<(B_DIM / N_BM) * (D_DIM / N_BN), 256, 0, stream>>>(
            xc, wenc_bf, b_enc, pre_act);
    } else {
        dim3 ggrid(B_DIM / G_BM, D_DIM / G_BN);
        gemm_enc_kernel<<<ggrid, 256, 0, stream>>>(xc, W_enc, b_enc, pre_act);
    }

    collect_kernel<<<(B_DIM * (D_DIM / 4)) / 256, 256, 0, stream>>>(pre_act, cnt, cidx, cval);

    select_topk_kernel<<<B_DIM, 256, 0, stream>>>(x, pre_bias, W_enc, b_enc, cnt, cidx, cval,
                                                  top_vals, top_idx);

    if (big_ws) {
        dim3 wtgrid(D_DIM / 64, H_DIM / 64);
        transpose_wdec_kernel<<<wtgrid, 256, 0, stream>>>(W_dec, wdecT);
        decode_rows_kernel<<<B_DIM, 256, 0, stream>>>(top_vals, top_idx, wdecT, pre_bias, x_hat);
    } else {
        decode_kernel<<<1280, 64, 0, stream>>>(top_vals, top_idx, W_dec, pre_bias, xhatt);
        dim3 tgrid(H_DIM / 64, B_DIM / 64);
        transpose_kernel<<<tgrid, 256, 0, stream>>>(xhatt, x_hat);
    }
}

// Round 8
// 1661.037 us; speedup vs baseline: 2.2168x; 1.3649x over previous
//
#include <hip/hip_runtime.h>
#include <hip/hip_bf16.h>
#include <cstdint>
#include <cstddef>
#include <math.h>

#define B_DIM 1024
#define H_DIM 4096
#define D_DIM 65536
#define K_TOP 64
#define CAND_CAP 512
#define RECOMP 96
#define RECOMP_PAD 128
#define COLLECT_THRESH 2.8f

typedef float f32x4 __attribute__((ext_vector_type(4)));
typedef __bf16 bf16x8 __attribute__((ext_vector_type(8)));
typedef unsigned short u16x8 __attribute__((ext_vector_type(8)));

__device__ inline unsigned short f2bf(float f) {
    unsigned int u = __float_as_uint(f);
    unsigned int r = u + 0x7FFFu + ((u >> 16) & 1u);   // RNE
    return (unsigned short)(r >> 16);
}
__device__ inline float bf2f(unsigned short s) {
    return __uint_as_float(((unsigned int)s) << 16);
}
// packed f32x2 -> bf16x2 (RNE), maps to v_cvt_pk_bf16_f32
__device__ inline unsigned int pk2bf(float a, float b) {
    __hip_bfloat162 h = __float22bfloat162_rn(make_float2(a, b));
    return *reinterpret_cast<unsigned int*>(&h);
}

// ---------------- Kernel 1: x_centered -> bf16 ----------------
__global__ void convert_x_kernel(const float* __restrict__ x,
                                 const float* __restrict__ pre_bias,
                                 unsigned short* __restrict__ xc) {
    int i = blockIdx.x * blockDim.x + threadIdx.x;      // quad index, total B*H/4
    float4 v = *(const float4*)&x[(size_t)i * 4];
    int h = (i * 4) & (H_DIM - 1);
    float4 pb = *(const float4*)&pre_bias[h];
    ushort4 o;
    o.x = f2bf(v.x - pb.x);
    o.y = f2bf(v.y - pb.y);
    o.z = f2bf(v.z - pb.z);
    o.w = f2bf(v.w - pb.w);
    *(ushort4*)&xc[(size_t)i * 4] = o;
}

// ---------------- Kernel 2 (main): bf16 MFMA GEMM, B converted in-staging,
//                  candidate-collect fused into the epilogue ----------------
#define N_BM 128
#define N_BN 128
#define N_BK 64

__global__ void __launch_bounds__(256, 3) gemm_enc_fused_kernel(
        const unsigned short* __restrict__ A,    // xc bf16 [B_DIM][H_DIM]
        const float* __restrict__ Wenc,          // [D_DIM][H_DIM] f32
        const float* __restrict__ b_enc,
        float* __restrict__ pre_act,
        int* __restrict__ cnt,
        int* __restrict__ cidx,
        float* __restrict__ cval) {
    __shared__ __align__(16) unsigned short sA[N_BM * N_BK];
    __shared__ __align__(16) unsigned short sB[N_BN * N_BK];

    const int tid = threadIdx.x;
    const int w = tid >> 6;
    const int l = tid & 63;
    const int bid = blockIdx.x;
    const int m0 = (((bid >> 3) & 7)) * N_BM;
    const int n0 = ((bid & 7) * 64 + (bid >> 6)) * N_BN;
    const int wm = w >> 1, wn = w & 1;
    const int lrow8 = l >> 3, lseg = l & 7;
    const int sw_seg = lseg ^ lrow8;          // pre-swizzled source / write slot

    f32x4 acc[4][4] = {};

    for (int k0 = 0; k0 < H_DIM; k0 += N_BK) {
        // stage A via global_load_lds (linear dest + pre-swizzled source)
        #pragma unroll
        for (int i = 0; i < 4; i++) {
            int rbase = w * 32 + i * 8;
            const unsigned short* src = &A[(size_t)(m0 + rbase + lrow8) * H_DIM + k0 + sw_seg * 8];
            __builtin_amdgcn_global_load_lds(
                (const __attribute__((address_space(1))) unsigned int*)src,
                (__attribute__((address_space(3))) unsigned int*)&sA[rbase * N_BK],
                16, 0, 0);
        }
        // stage B from f32 W_enc with packed bf16 convert, swizzled ds_write
        #pragma unroll
        for (int i = 0; i < 4; i++) {
            int row = w * 32 + i * 8 + lrow8;             // row&7 == lrow8
            const float* src = &Wenc[(size_t)(n0 + row) * H_DIM + k0 + lseg * 8];
            float4 f0 = *(const float4*)src;
            float4 f1 = *(const float4*)(src + 4);
            uint4 o;
            o.x = pk2bf(f0.x, f0.y);
            o.y = pk2bf(f0.z, f0.w);
            o.z = pk2bf(f1.x, f1.y);
            o.w = pk2bf(f1.z, f1.w);
            *(uint4*)&sB[row * N_BK + sw_seg * 8] = o;
        }
        __syncthreads();

        #pragma unroll
        for (int ks = 0; ks < 2; ks++) {
            const int slot = ks * 4 + (l >> 4);
            const int rslot = (slot ^ (l & 7)) * 8;       // read-side swizzle
            bf16x8 bfr[4];
            #pragma unroll
            for (int nj = 0; nj < 4; nj++) {
                int r = wn * 64 + nj * 16 + (l & 15);
                bfr[nj] = *(bf16x8*)&sB[r * N_BK + rslot];
            }
            #pragma unroll
            for (int mi = 0; mi < 4; mi++) {
                int r = wm * 64 + mi * 16 + (l & 15);
                bf16x8 afr = *(bf16x8*)&sA[r * N_BK + rslot];
                #pragma unroll
                for (int nj = 0; nj < 4; nj++)
                    acc[mi][nj] = __builtin_amdgcn_mfma_f32_16x16x32_bf16(afr, bfr[nj], acc[mi][nj], 0, 0, 0);
            }
        }
        __syncthreads();
    }

    // epilogue: write pre_act AND collect candidates (> THRESH) in one pass
    const int lc = l & 15, lr4 = (l >> 4) * 4;
    #pragma unroll
    for (int nj = 0; nj < 4; nj++) {
        int col = n0 + wn * 64 + nj * 16 + lc;
        float bias = b_enc[col];
        #pragma unroll
        for (int mi = 0; mi < 4; mi++) {
            int row = m0 + wm * 64 + mi * 16 + lr4;
            #pragma unroll
            for (int e = 0; e < 4; e++) {
                float v = acc[mi][nj][e] + bias;
                pre_act[(size_t)(row + e) * D_DIM + col] = v;
                if (v > COLLECT_THRESH) {
                    int b = row + e;
                    int p = atomicAdd(&cnt[b], 1);
                    if (p < CAND_CAP) {
                        cidx[b * CAND_CAP + p] = col;
                        cval[b * CAND_CAP + p] = v;
                    }
                }
            }
        }
    }
}

// ---------------- Fallback (ws too small): round-5 GEMM + separate collect ----------------
#define G_BM 256
#define G_BN 128
#define G_BK 64

__global__ void __launch_bounds__(256) gemm_enc_kernel(
        const unsigned short* __restrict__ A,
        const float* __restrict__ Wenc,
        const float* __restrict__ b_enc,
        float* __restrict__ pre_act) {
    __shared__ __align__(16) unsigned short sA[G_BM * G_BK];
    __shared__ __align__(16) unsigned short sB[G_BN * G_BK];

    const int tid = threadIdx.x;
    const int w = tid >> 6;
    const int l = tid & 63;
    const int m0 = blockIdx.x * G_BM;
    const int n0 = blockIdx.y * G_BN;
    const int wm = w >> 1, wn = w & 1;
    const int lrow8 = l >> 3, lseg = l & 7;
    const int sw_seg = lseg ^ lrow8;

    f32x4 acc[8][4] = {};

    for (int k0 = 0; k0 < H_DIM; k0 += G_BK) {
        #pragma unroll
        for (int i = 0; i < 8; i++) {
            int row = w * 64 + i * 8 + lrow8;
            const unsigned short* src = &A[(size_t)(m0 + row) * H_DIM + k0 + sw_seg * 8];
            __builtin_amdgcn_global_load_lds(
                (const __attribute__((address_space(1))) unsigned int*)src,
                (__attribute__((address_space(3))) unsigned int*)&sA[(w * 64 + i * 8) * G_BK],
                16, 0, 0);
        }
        #pragma unroll
        for (int i = 0; i < 4; i++) {
            int row = w * 32 + i * 8 + lrow8;
            const float* src = &Wenc[(size_t)(n0 + row) * H_DIM + k0 + lseg * 8];
            float4 f0 = *(const float4*)src;
            float4 f1 = *(const float4*)(src + 4);
            u16x8 o;
            o[0] = f2bf(f0.x); o[1] = f2bf(f0.y); o[2] = f2bf(f0.z); o[3] = f2bf(f0.w);
            o[4] = f2bf(f1.x); o[5] = f2bf(f1.y); o[6] = f2bf(f1.z); o[7] = f2bf(f1.w);
            *(u16x8*)&sB[row * G_BK + sw_seg * 8] = o;
        }
        __syncthreads();

        #pragma unroll
        for (int ks = 0; ks < 2; ks++) {
            const int slot = ks * 4 + (l >> 4);
            const int rslot = (slot ^ (l & 7)) * 8;
            bf16x8 bfr[4];
            #pragma unroll
            for (int nj = 0; nj < 4; nj++) {
                int r = wn * 64 + nj * 16 + (l & 15);
                bfr[nj] = *(bf16x8*)&sB[r * G_BK + rslot];
            }
            #pragma unroll
            for (int mi = 0; mi < 8; mi++) {
                int r = wm * 128 + mi * 16 + (l & 15);
                bf16x8 afr = *(bf16x8*)&sA[r * G_BK + rslot];
                #pragma unroll
                for (int nj = 0; nj < 4; nj++)
                    acc[mi][nj] = __builtin_amdgcn_mfma_f32_16x16x32_bf16(afr, bfr[nj], acc[mi][nj], 0, 0, 0);
            }
        }
        __syncthreads();
    }

    const int lc = l & 15, lr4 = (l >> 4) * 4;
    #pragma unroll
    for (int nj = 0; nj < 4; nj++) {
        int col = n0 + wn * 64 + nj * 16 + lc;
        float bias = b_enc[col];
        #pragma unroll
        for (int mi = 0; mi < 8; mi++) {
            int row = m0 + wm * 128 + mi * 16 + lr4;
            #pragma unroll
            for (int e = 0; e < 4; e++) {
                pre_act[(size_t)(row + e) * D_DIM + col] = acc[mi][nj][e] + bias;
            }
        }
    }
}

__global__ void collect_kernel(const float* __restrict__ pre_act,
                               int* __restrict__ cnt,
                               int* __restrict__ cidx,
                               float* __restrict__ cval) {
    int i = blockIdx.x * blockDim.x + threadIdx.x;
    float4 v = *(const float4*)&pre_act[(size_t)i * 4];
    float fv[4] = {v.x, v.y, v.z, v.w};
    int base = i * 4;
    #pragma unroll
    for (int e = 0; e < 4; e++) {
        if (fv[e] > COLLECT_THRESH) {
            int idx = base + e;
            int b = idx >> 16;
            int d = idx & (D_DIM - 1);
            int p = atomicAdd(&cnt[b], 1);
            if (p < CAND_CAP) {
                cidx[b * CAND_CAP + p] = d;
                cval[b * CAND_CAP + p] = fv[e];
            }
        }
    }
}

// ---------------- Kernel 4: approx sort -> f64 recompute (WITH bias) -> exact top-64 ----------------
__global__ void __launch_bounds__(256) select_topk_kernel(
        const float* __restrict__ x, const float* __restrict__ pre_bias,
        const float* __restrict__ Wenc, const float* __restrict__ b_enc,
        const int* __restrict__ cnt, const int* __restrict__ cidx, const float* __restrict__ cval,
        float* __restrict__ out_vals, float* __restrict__ out_idx) {
    __shared__ float s_val[CAND_CAP];
    __shared__ int   s_idx[CAND_CAP];
    __shared__ __align__(16) float s_x[H_DIM];
    __shared__ double s_dv[RECOMP_PAD];
    __shared__ int    s_di[RECOMP_PAD];

    const int b = blockIdx.x;
    const int tid = threadIdx.x;

    for (int i = tid; i < H_DIM / 4; i += 256) {
        float4 xv = *(const float4*)&x[(size_t)b * H_DIM + i * 4];
        float4 pb = *(const float4*)&pre_bias[i * 4];
        xv.x -= pb.x; xv.y -= pb.y; xv.z -= pb.z; xv.w -= pb.w;
        *(float4*)&s_x[i * 4] = xv;
    }
    const int n = min(cnt[b], CAND_CAP);
    for (int i = tid; i < CAND_CAP; i += 256) {
        if (i < n) { s_val[i] = cval[b * CAND_CAP + i]; s_idx[i] = cidx[b * CAND_CAP + i]; }
        else       { s_val[i] = -1e30f;                 s_idx[i] = 0x7FFFFFFF; }
    }
    __syncthreads();

    // bitonic sort 512 by approx value desc, tie idx asc
    for (int k = 2; k <= CAND_CAP; k <<= 1) {
        for (int j = k >> 1; j > 0; j >>= 1) {
            int p = tid;
            int i1 = (p / j) * 2 * j + (p % j);
            int i2 = i1 + j;
            bool up = ((i1 & k) == 0);
            float v1 = s_val[i1], v2 = s_val[i2];
            int  d1 = s_idx[i1],  d2 = s_idx[i2];
            bool before12 = (v1 > v2) || (v1 == v2 && d1 < d2);
            bool before21 = (v2 > v1) || (v2 == v1 && d2 < d1);
            bool sw = up ? before21 : before12;
            __syncthreads();
            if (sw) { s_val[i1] = v2; s_val[i2] = v1; s_idx[i1] = d2; s_idx[i2] = d1; }
            __syncthreads();
        }
    }

    // f64 recompute of the top-RECOMP approx candidates, INCLUDING b_enc
    const int T = min(RECOMP, n);
    double dv = -1e300;
    int di = 0x7FFFFFFF;
    if (tid < T) {
        di = s_idx[tid];
        const float* wr = &Wenc[(size_t)di * H_DIM];
        double a0 = 0, a1 = 0, a2 = 0, a3 = 0;
        for (int h = 0; h < H_DIM; h += 4) {
            float4 wv = *(const float4*)&wr[h];
            float4 xv = *(const float4*)&s_x[h];
            a0 += (double)xv.x * (double)wv.x;
            a1 += (double)xv.y * (double)wv.y;
            a2 += (double)xv.z * (double)wv.z;
            a3 += (double)xv.w * (double)wv.w;
        }
        dv = ((a0 + a1) + (a2 + a3)) + (double)b_enc[di];
    }
    __syncthreads();
    if (tid < RECOMP_PAD) { s_dv[tid] = (tid < T) ? dv : -1e300; s_di[tid] = di; }

    // bitonic sort 128 on f64 values (desc, tie idx asc)
    for (int k = 2; k <= RECOMP_PAD; k <<= 1) {
        for (int j = k >> 1; j > 0; j >>= 1) {
            __syncthreads();
            if (tid < RECOMP_PAD / 2) {
                int p = tid;
                int i1 = (p / j) * 2 * j + (p % j);
                int i2 = i1 + j;
                bool up = ((i1 & k) == 0);
                double v1 = s_dv[i1], v2 = s_dv[i2];
                int  d1 = s_di[i1],  d2 = s_di[i2];
                bool before12 = (v1 > v2) || (v1 == v2 && d1 < d2);
                bool before21 = (v2 > v1) || (v2 == v1 && d2 < d1);
                bool sw = up ? before21 : before12;
                if (sw) { s_dv[i1] = v2; s_dv[i2] = v1; s_di[i1] = d2; s_di[i2] = d1; }
            }
        }
    }
    __syncthreads();
    if (tid < K_TOP) {
        double v = s_dv[tid];
        out_vals[b * K_TOP + tid] = (float)(v > 0.0 ? v : 0.0);
        out_idx[b * K_TOP + tid]  = (float)s_di[tid];
    }
}

// ---------------- Kernel 5a: W_dec [H][D] f32 -> W_dec^T [D][H] bf16 ----------------
__global__ void __launch_bounds__(256) transpose_wdec_kernel(
        const float* __restrict__ Wdec, unsigned short* __restrict__ WdecT) {
    __shared__ float tile[64][65];
    const int d0 = blockIdx.x * 64;
    const int h0 = blockIdx.y * 64;
    const int tc = threadIdx.x & 63, tr = threadIdx.x >> 6;
    #pragma unroll
    for (int hh = tr; hh < 64; hh += 4)
        tile[hh][tc] = Wdec[(size_t)(h0 + hh) * D_DIM + d0 + tc];
    __syncthreads();
    #pragma unroll
    for (int dd = tr; dd < 64; dd += 4)
        WdecT[(size_t)(d0 + dd) * H_DIM + h0 + tc] = f2bf(tile[tc][dd]);
}

// ---------------- Kernel 5b: decode as scaled row-sum over W_dec^T ----------------
__global__ void __launch_bounds__(256) decode_rows_kernel(
        const float* __restrict__ out_vals,
        const float* __restrict__ out_idx,
        const unsigned short* __restrict__ WdecT,
        const float* __restrict__ pre_bias,
        float* __restrict__ x_hat) {
    __shared__ float s_v[K_TOP];
    __shared__ int   s_d[K_TOP];
    const int b = blockIdx.x;
    const int t = threadIdx.x;

    if (t < K_TOP) {
        s_v[t] = out_vals[b * K_TOP + t];
        s_d[t] = (int)out_idx[b * K_TOP + t];
    }
    __syncthreads();

    float acc[16] = {};
    #pragma unroll 4
    for (int j = 0; j < K_TOP; j++) {
        float v = s_v[j];
        const unsigned short* wr = &WdecT[(size_t)s_d[j] * H_DIM];
        u16x8 w0 = *(const u16x8*)&wr[t * 8];
        u16x8 w1 = *(const u16x8*)&wr[2048 + t * 8];
        #pragma unroll
        for (int e = 0; e < 8; e++) {
            acc[e]     = fmaf(v, bf2f(w0[e]), acc[e]);
            acc[8 + e] = fmaf(v, bf2f(w1[e]), acc[8 + e]);
        }
    }
    #pragma unroll
    for (int c = 0; c < 2; c++) {
        int h = c * 2048 + t * 8;
        float4 pb0 = *(const float4*)&pre_bias[h];
        float4 pb1 = *(const float4*)&pre_bias[h + 4];
        float4 o0, o1;
        o0.x = acc[c*8+0] + pb0.x; o0.y = acc[c*8+1] + pb0.y;
        o0.z = acc[c*8+2] + pb0.z; o0.w = acc[c*8+3] + pb0.w;
        o1.x = acc[c*8+4] + pb1.x; o1.y = acc[c*8+5] + pb1.y;
        o1.z = acc[c*8+6] + pb1.z; o1.w = acc[c*8+7] + pb1.w;
        *(float4*)&x_hat[(size_t)b * H_DIM + h]     = o0;
        *(float4*)&x_hat[(size_t)b * H_DIM + h + 4] = o1;
    }
}

// ---------------- Fallback decode (ws too small) ----------------
__global__ void __launch_bounds__(64) decode_kernel(
        const float* __restrict__ out_vals,
        const float* __restrict__ out_idx,
        const float* __restrict__ Wdec,
        const float* __restrict__ pre_bias,
        float* __restrict__ x_hat_t) {
    __shared__ float2 s_vi[64 * 64];
    const int lane = threadIdx.x;
    const int s0 = (blockIdx.x >> 3) & 15;

    for (int i = lane; i < 64 * 64; i += 64) {
        int j = i >> 6, bb = i & 63;
        int b = s0 * 64 + bb;
        float v = out_vals[b * K_TOP + j];
        int id = (int)out_idx[b * K_TOP + j];
        s_vi[i] = make_float2(v, __int_as_float(id << 2));
    }
    __syncthreads();

    const int b = s0 * 64 + lane;
    for (int wi = blockIdx.x; wi < H_DIM * 16; wi += 1280) {
        const int h = (wi & 7) + ((wi >> 7) << 3);
        const char* wr = (const char*)(Wdec + (size_t)h * D_DIM);
        float acc = 0.0f;
        #pragma unroll 8
        for (int j = 0; j < K_TOP; j++) {
            float2 vi = s_vi[j * 64 + lane];
            acc = fmaf(vi.x, *(const float*)(wr + __float_as_int(vi.y)), acc);
        }
        x_hat_t[(size_t)h * B_DIM + b] = acc + pre_bias[h];
    }
}

__global__ void __launch_bounds__(256) transpose_kernel(const float* __restrict__ xt,
                                                        float* __restrict__ x_hat) {
    __shared__ float tile[64][65];
    const int hb = blockIdx.x * 64;
    const int bb = blockIdx.y * 64;
    const int tc = threadIdx.x & 63, tr = threadIdx.x >> 6;
    #pragma unroll
    for (int r = tr; r < 64; r += 4)
        tile[r][tc] = xt[(size_t)(hb + r) * B_DIM + bb + tc];
    __syncthreads();
    #pragma unroll
    for (int r = tr; r < 64; r += 4)
        x_hat[(size_t)(bb + r) * H_DIM + hb + tc] = tile[tc][r];
}

// ---------------- launch ----------------
extern "C" void kernel_launch(void* const* d_in, const int* in_sizes, int n_in,
                              void* d_out, int out_size, void* d_ws, size_t ws_size,
                              hipStream_t stream) {
    const float* x        = (const float*)d_in[0];
    const float* W_enc    = (const float*)d_in[1];
    const float* b_enc    = (const float*)d_in[2];
    const float* W_dec    = (const float*)d_in[3];
    const float* pre_bias = (const float*)d_in[4];

    float* out = (float*)d_out;
    float* x_hat    = out;
    float* top_vals = out + (size_t)B_DIM * H_DIM;
    float* top_idx  = top_vals + (size_t)B_DIM * K_TOP;
    float* pre_act  = top_idx + (size_t)B_DIM * K_TOP;

    // workspace layout
    unsigned short* xc = (unsigned short*)d_ws;                               // [0, 8MB)
    int*   cidx  = (int*)((char*)d_ws + (size_t)B_DIM * H_DIM * 2);           // [8, 10MB)
    float* cval  = (float*)((char*)cidx + (size_t)B_DIM * CAND_CAP * 4);      // [10, 12MB)
    int*   cnt   = (int*)((char*)cval + (size_t)B_DIM * CAND_CAP * 4);        // [12MB, +4KB)
    float* xhatt = (float*)((char*)cnt + 4096);                               // fallback only
    const size_t WDT_OFF = 32ull << 20;                                       // 32 MB aligned
    unsigned short* wdecT = (unsigned short*)((char*)d_ws + WDT_OFF);         // 512 MB
    const bool big_ws = ws_size >= WDT_OFF + ((size_t)D_DIM * H_DIM * 2) + (1 << 20);

    hipMemsetAsync(cnt, 0, B_DIM * sizeof(int), stream);

    convert_x_kernel<<<(B_DIM * H_DIM / 4) / 256, 256, 0, stream>>>(x, pre_bias, xc);

    if (big_ws) {
        gemm_enc_fused_kernel<<<(B_DIM / N_BM) * (D_DIM / N_BN), 256, 0, stream>>>(
            xc, W_enc, b_enc, pre_act, cnt, cidx, cval);
    } else {
        dim3 ggrid(B_DIM / G_BM, D_DIM / G_BN);
        gemm_enc_kernel<<<ggrid, 256, 0, stream>>>(xc, W_enc, b_enc, pre_act);
        collect_kernel<<<(B_DIM * (D_DIM / 4)) / 256, 256, 0, stream>>>(pre_act, cnt, cidx, cval);
    }

    select_topk_kernel<<<B_DIM, 256, 0, stream>>>(x, pre_bias, W_enc, b_enc, cnt, cidx, cval,
                                                  top_vals, top_idx);

    if (big_ws) {
        dim3 wtgrid(D_DIM / 64, H_DIM / 64);
        transpose_wdec_kernel<<<wtgrid, 256, 0, stream>>>(W_dec, wdecT);
        decode_rows_kernel<<<B_DIM, 256, 0, stream>>>(top_vals, top_idx, wdecT, pre_bias, x_hat);
    } else {
        decode_kernel<<<1280, 64, 0, stream>>>(top_vals, top_idx, W_dec, pre_bias, xhatt);
        dim3 tgrid(H_DIM / 64, B_DIM / 64);
        transpose_kernel<<<tgrid, 256, 0, stream>>>(xhatt, x_hat);
    }
}

// Round 9
// 1431.961 us; speedup vs baseline: 2.5714x; 1.1600x over previous
//
#include <hip/hip_runtime.h>
#include <hip/hip_bf16.h>
#include <cstdint>
#include <cstddef>
#include <math.h>

#define B_DIM 1024
#define H_DIM 4096
#define D_DIM 65536
#define K_TOP 64
#define CAND_CAP 512
#define RECOMP 96
#define RECOMP_PAD 128
#define COLLECT_THRESH 2.8f

typedef float f32x4 __attribute__((ext_vector_type(4)));
typedef __bf16 bf16x8 __attribute__((ext_vector_type(8)));
typedef unsigned short u16x8 __attribute__((ext_vector_type(8)));

__device__ inline unsigned short f2bf(float f) {
    unsigned int u = __float_as_uint(f);
    unsigned int r = u + 0x7FFFu + ((u >> 16) & 1u);   // RNE
    return (unsigned short)(r >> 16);
}
__device__ inline float bf2f(unsigned short s) {
    return __uint_as_float(((unsigned int)s) << 16);
}
__device__ inline unsigned int pk2bf(float a, float b) {
    __hip_bfloat162 h = __float22bfloat162_rn(make_float2(a, b));
    return *reinterpret_cast<unsigned int*>(&h);
}

// ---------------- Kernel 1: x_centered -> bf16 ----------------
__global__ void convert_x_kernel(const float* __restrict__ x,
                                 const float* __restrict__ pre_bias,
                                 unsigned short* __restrict__ xc) {
    int i = blockIdx.x * blockDim.x + threadIdx.x;
    float4 v = *(const float4*)&x[(size_t)i * 4];
    int h = (i * 4) & (H_DIM - 1);
    float4 pb = *(const float4*)&pre_bias[h];
    ushort4 o;
    o.x = f2bf(v.x - pb.x);
    o.y = f2bf(v.y - pb.y);
    o.z = f2bf(v.z - pb.z);
    o.w = f2bf(v.w - pb.w);
    *(ushort4*)&xc[(size_t)i * 4] = o;
}

// ---------------- Kernel 2 (main): heterogeneous dispatch ----------------
// Blocks [0, 4096):   bf16 MFMA GEMM (B converted in staging, collect fused)
// Blocks [4096, 8192): W_dec [H][D] f32 -> W_dec^T [D][H] bf16 (16 tiles each)
// The transpose's 1.6 GB of streaming traffic hides under the latency-bound GEMM.
#define N_BM 128
#define N_BN 128
#define N_BK 64
#define NGEMM_BLK ((B_DIM / N_BM) * (D_DIM / N_BN))   // 4096
#define NTW_BLK 4096
#define NTILES (D_DIM / 64 * (H_DIM / 64))            // 65536

__global__ void __launch_bounds__(256, 3) gemm_twdec_kernel(
        const unsigned short* __restrict__ A,    // xc bf16 [B][H]
        const float* __restrict__ Wenc,          // [D][H] f32
        const float* __restrict__ b_enc,
        float* __restrict__ pre_act,
        int* __restrict__ cnt,
        int* __restrict__ cidx,
        float* __restrict__ cval,
        const float* __restrict__ Wdec,          // [H][D] f32
        unsigned short* __restrict__ WdecT) {    // [D][H] bf16
    __shared__ union {
        struct { __align__(16) unsigned short A[N_BM * N_BK];
                 __align__(16) unsigned short B[N_BN * N_BK]; } g;   // 32 KB
        float t[64][65];                                             // 16.6 KB
    } lds;

    const int tid = threadIdx.x;
    const int bid = blockIdx.x;

    if (bid >= NGEMM_BLK) {
        // ---- transpose path ----
        const int tb = bid - NGEMM_BLK;
        const int tc = tid & 63, tr = tid >> 6;
        for (int t = tb; t < NTILES; t += NTW_BLK) {
            const int d0 = (t & 1023) << 6;
            const int h0 = (t >> 10) << 6;
            #pragma unroll
            for (int hh = tr; hh < 64; hh += 4)
                lds.t[hh][tc] = Wdec[(size_t)(h0 + hh) * D_DIM + d0 + tc];
            __syncthreads();
            #pragma unroll
            for (int dd = tr; dd < 64; dd += 4)
                WdecT[(size_t)(d0 + dd) * H_DIM + h0 + tc] = f2bf(lds.t[tc][dd]);
            __syncthreads();
        }
        return;
    }

    // ---- GEMM path (identical math to round 8) ----
    const int w = tid >> 6;
    const int l = tid & 63;
    const int m0 = (((bid >> 3) & 7)) * N_BM;
    const int n0 = ((bid & 7) * 64 + (bid >> 6)) * N_BN;
    const int wm = w >> 1, wn = w & 1;
    const int lrow8 = l >> 3, lseg = l & 7;
    const int sw_seg = lseg ^ lrow8;

    f32x4 acc[4][4] = {};

    for (int k0 = 0; k0 < H_DIM; k0 += N_BK) {
        #pragma unroll
        for (int i = 0; i < 4; i++) {
            int rbase = w * 32 + i * 8;
            const unsigned short* src = &A[(size_t)(m0 + rbase + lrow8) * H_DIM + k0 + sw_seg * 8];
            __builtin_amdgcn_global_load_lds(
                (const __attribute__((address_space(1))) unsigned int*)src,
                (__attribute__((address_space(3))) unsigned int*)&lds.g.A[rbase * N_BK],
                16, 0, 0);
        }
        #pragma unroll
        for (int i = 0; i < 4; i++) {
            int row = w * 32 + i * 8 + lrow8;
            const float* src = &Wenc[(size_t)(n0 + row) * H_DIM + k0 + lseg * 8];
            float4 f0 = *(const float4*)src;
            float4 f1 = *(const float4*)(src + 4);
            uint4 o;
            o.x = pk2bf(f0.x, f0.y);
            o.y = pk2bf(f0.z, f0.w);
            o.z = pk2bf(f1.x, f1.y);
            o.w = pk2bf(f1.z, f1.w);
            *(uint4*)&lds.g.B[row * N_BK + sw_seg * 8] = o;
        }
        __syncthreads();

        #pragma unroll
        for (int ks = 0; ks < 2; ks++) {
            const int slot = ks * 4 + (l >> 4);
            const int rslot = (slot ^ (l & 7)) * 8;
            bf16x8 bfr[4];
            #pragma unroll
            for (int nj = 0; nj < 4; nj++) {
                int r = wn * 64 + nj * 16 + (l & 15);
                bfr[nj] = *(bf16x8*)&lds.g.B[r * N_BK + rslot];
            }
            #pragma unroll
            for (int mi = 0; mi < 4; mi++) {
                int r = wm * 64 + mi * 16 + (l & 15);
                bf16x8 afr = *(bf16x8*)&lds.g.A[r * N_BK + rslot];
                #pragma unroll
                for (int nj = 0; nj < 4; nj++)
                    acc[mi][nj] = __builtin_amdgcn_mfma_f32_16x16x32_bf16(afr, bfr[nj], acc[mi][nj], 0, 0, 0);
            }
        }
        __syncthreads();
    }

    const int lc = l & 15, lr4 = (l >> 4) * 4;
    #pragma unroll
    for (int nj = 0; nj < 4; nj++) {
        int col = n0 + wn * 64 + nj * 16 + lc;
        float bias = b_enc[col];
        #pragma unroll
        for (int mi = 0; mi < 4; mi++) {
            int row = m0 + wm * 64 + mi * 16 + lr4;
            #pragma unroll
            for (int e = 0; e < 4; e++) {
                float v = acc[mi][nj][e] + bias;
                pre_act[(size_t)(row + e) * D_DIM + col] = v;
                if (v > COLLECT_THRESH) {
                    int b = row + e;
                    int p = atomicAdd(&cnt[b], 1);
                    if (p < CAND_CAP) {
                        cidx[b * CAND_CAP + p] = col;
                        cval[b * CAND_CAP + p] = v;
                    }
                }
            }
        }
    }
}

// ---------------- Kernel 4 (main): select top-64 + fused decode ----------------
__global__ void __launch_bounds__(256) select_decode_kernel(
        const float* __restrict__ x, const float* __restrict__ pre_bias,
        const float* __restrict__ Wenc, const float* __restrict__ b_enc,
        const int* __restrict__ cnt, const int* __restrict__ cidx, const float* __restrict__ cval,
        const unsigned short* __restrict__ WdecT,
        float* __restrict__ out_vals, float* __restrict__ out_idx,
        float* __restrict__ x_hat) {
    __shared__ float s_val[CAND_CAP];
    __shared__ int   s_idx[CAND_CAP];
    __shared__ __align__(16) float s_x[H_DIM];
    __shared__ double s_dv[RECOMP_PAD];
    __shared__ int    s_di[RECOMP_PAD];
    __shared__ float  s_v2[K_TOP];
    __shared__ int    s_d2[K_TOP];

    const int b = blockIdx.x;
    const int tid = threadIdx.x;

    for (int i = tid; i < H_DIM / 4; i += 256) {
        float4 xv = *(const float4*)&x[(size_t)b * H_DIM + i * 4];
        float4 pb = *(const float4*)&pre_bias[i * 4];
        xv.x -= pb.x; xv.y -= pb.y; xv.z -= pb.z; xv.w -= pb.w;
        *(float4*)&s_x[i * 4] = xv;
    }
    const int n = min(cnt[b], CAND_CAP);
    for (int i = tid; i < CAND_CAP; i += 256) {
        if (i < n) { s_val[i] = cval[b * CAND_CAP + i]; s_idx[i] = cidx[b * CAND_CAP + i]; }
        else       { s_val[i] = -1e30f;                 s_idx[i] = 0x7FFFFFFF; }
    }
    __syncthreads();

    // bitonic sort 512 by approx value desc, tie idx asc
    for (int k = 2; k <= CAND_CAP; k <<= 1) {
        for (int j = k >> 1; j > 0; j >>= 1) {
            int p = tid;
            int i1 = (p / j) * 2 * j + (p % j);
            int i2 = i1 + j;
            bool up = ((i1 & k) == 0);
            float v1 = s_val[i1], v2 = s_val[i2];
            int  d1 = s_idx[i1],  d2 = s_idx[i2];
            bool before12 = (v1 > v2) || (v1 == v2 && d1 < d2);
            bool before21 = (v2 > v1) || (v2 == v1 && d2 < d1);
            bool sw = up ? before21 : before12;
            __syncthreads();
            if (sw) { s_val[i1] = v2; s_val[i2] = v1; s_idx[i1] = d2; s_idx[i2] = d1; }
            __syncthreads();
        }
    }

    // f64 recompute of the top-RECOMP approx candidates, INCLUDING b_enc
    const int T = min(RECOMP, n);
    double dv = -1e300;
    int di = 0x7FFFFFFF;
    if (tid < T) {
        di = s_idx[tid];
        const float* wr = &Wenc[(size_t)di * H_DIM];
        double a0 = 0, a1 = 0, a2 = 0, a3 = 0;
        for (int h = 0; h < H_DIM; h += 4) {
            float4 wv = *(const float4*)&wr[h];
            float4 xv = *(const float4*)&s_x[h];
            a0 += (double)xv.x * (double)wv.x;
            a1 += (double)xv.y * (double)wv.y;
            a2 += (double)xv.z * (double)wv.z;
            a3 += (double)xv.w * (double)wv.w;
        }
        dv = ((a0 + a1) + (a2 + a3)) + (double)b_enc[di];
    }
    __syncthreads();
    if (tid < RECOMP_PAD) { s_dv[tid] = (tid < T) ? dv : -1e300; s_di[tid] = di; }

    // bitonic sort 128 on f64 values (desc, tie idx asc)
    for (int k = 2; k <= RECOMP_PAD; k <<= 1) {
        for (int j = k >> 1; j > 0; j >>= 1) {
            __syncthreads();
            if (tid < RECOMP_PAD / 2) {
                int p = tid;
                int i1 = (p / j) * 2 * j + (p % j);
                int i2 = i1 + j;
                bool up = ((i1 & k) == 0);
                double v1 = s_dv[i1], v2 = s_dv[i2];
                int  d1 = s_di[i1],  d2 = s_di[i2];
                bool before12 = (v1 > v2) || (v1 == v2 && d1 < d2);
                bool before21 = (v2 > v1) || (v2 == v1 && d2 < d1);
                bool sw = up ? before21 : before12;
                if (sw) { s_dv[i1] = v2; s_dv[i2] = v1; s_di[i1] = d2; s_di[i2] = d1; }
            }
        }
    }
    __syncthreads();
    if (tid < K_TOP) {
        double v = s_dv[tid];
        float rv = (float)(v > 0.0 ? v : 0.0);
        out_vals[b * K_TOP + tid] = rv;
        out_idx[b * K_TOP + tid]  = (float)s_di[tid];
        s_v2[tid] = rv;
        s_d2[tid] = s_di[tid];
    }
    __syncthreads();

    // ---- fused decode: x_hat[b][:] = sum_j v_j * WdecT[d_j][:] + pre_bias ----
    const int t = tid;
    float acc[16] = {};
    #pragma unroll 4
    for (int j = 0; j < K_TOP; j++) {
        float v = s_v2[j];
        const unsigned short* wr = &WdecT[(size_t)s_d2[j] * H_DIM];
        u16x8 w0 = *(const u16x8*)&wr[t * 8];
        u16x8 w1 = *(const u16x8*)&wr[2048 + t * 8];
        #pragma unroll
        for (int e = 0; e < 8; e++) {
            acc[e]     = fmaf(v, bf2f(w0[e]), acc[e]);
            acc[8 + e] = fmaf(v, bf2f(w1[e]), acc[8 + e]);
        }
    }
    #pragma unroll
    for (int c = 0; c < 2; c++) {
        int h = c * 2048 + t * 8;
        float4 pb0 = *(const float4*)&pre_bias[h];
        float4 pb1 = *(const float4*)&pre_bias[h + 4];
        float4 o0, o1;
        o0.x = acc[c*8+0] + pb0.x; o0.y = acc[c*8+1] + pb0.y;
        o0.z = acc[c*8+2] + pb0.z; o0.w = acc[c*8+3] + pb0.w;
        o1.x = acc[c*8+4] + pb1.x; o1.y = acc[c*8+5] + pb1.y;
        o1.z = acc[c*8+6] + pb1.z; o1.w = acc[c*8+7] + pb1.w;
        *(float4*)&x_hat[(size_t)b * H_DIM + h]     = o0;
        *(float4*)&x_hat[(size_t)b * H_DIM + h + 4] = o1;
    }
}

// ================= fallback path (ws too small) =================
#define G_BM 256
#define G_BN 128
#define G_BK 64

__global__ void __launch_bounds__(256) gemm_enc_kernel(
        const unsigned short* __restrict__ A,
        const float* __restrict__ Wenc,
        const float* __restrict__ b_enc,
        float* __restrict__ pre_act) {
    __shared__ __align__(16) unsigned short sA[G_BM * G_BK];
    __shared__ __align__(16) unsigned short sB[G_BN * G_BK];

    const int tid = threadIdx.x;
    const int w = tid >> 6;
    const int l = tid & 63;
    const int m0 = blockIdx.x * G_BM;
    const int n0 = blockIdx.y * G_BN;
    const int wm = w >> 1, wn = w & 1;
    const int lrow8 = l >> 3, lseg = l & 7;
    const int sw_seg = lseg ^ lrow8;

    f32x4 acc[8][4] = {};

    for (int k0 = 0; k0 < H_DIM; k0 += G_BK) {
        #pragma unroll
        for (int i = 0; i < 8; i++) {
            int row = w * 64 + i * 8 + lrow8;
            const unsigned short* src = &A[(size_t)(m0 + row) * H_DIM + k0 + sw_seg * 8];
            __builtin_amdgcn_global_load_lds(
                (const __attribute__((address_space(1))) unsigned int*)src,
                (__attribute__((address_space(3))) unsigned int*)&sA[(w * 64 + i * 8) * G_BK],
                16, 0, 0);
        }
        #pragma unroll
        for (int i = 0; i < 4; i++) {
            int row = w * 32 + i * 8 + lrow8;
            const float* src = &Wenc[(size_t)(n0 + row) * H_DIM + k0 + lseg * 8];
            float4 f0 = *(const float4*)src;
            float4 f1 = *(const float4*)(src + 4);
            u16x8 o;
            o[0] = f2bf(f0.x); o[1] = f2bf(f0.y); o[2] = f2bf(f0.z); o[3] = f2bf(f0.w);
            o[4] = f2bf(f1.x); o[5] = f2bf(f1.y); o[6] = f2bf(f1.z); o[7] = f2bf(f1.w);
            *(u16x8*)&sB[row * G_BK + sw_seg * 8] = o;
        }
        __syncthreads();

        #pragma unroll
        for (int ks = 0; ks < 2; ks++) {
            const int slot = ks * 4 + (l >> 4);
            const int rslot = (slot ^ (l & 7)) * 8;
            bf16x8 bfr[4];
            #pragma unroll
            for (int nj = 0; nj < 4; nj++) {
                int r = wn * 64 + nj * 16 + (l & 15);
                bfr[nj] = *(bf16x8*)&sB[r * G_BK + rslot];
            }
            #pragma unroll
            for (int mi = 0; mi < 8; mi++) {
                int r = wm * 128 + mi * 16 + (l & 15);
                bf16x8 afr = *(bf16x8*)&sA[r * G_BK + rslot];
                #pragma unroll
                for (int nj = 0; nj < 4; nj++)
                    acc[mi][nj] = __builtin_amdgcn_mfma_f32_16x16x32_bf16(afr, bfr[nj], acc[mi][nj], 0, 0, 0);
            }
        }
        __syncthreads();
    }

    const int lc = l & 15, lr4 = (l >> 4) * 4;
    #pragma unroll
    for (int nj = 0; nj < 4; nj++) {
        int col = n0 + wn * 64 + nj * 16 + lc;
        float bias = b_enc[col];
        #pragma unroll
        for (int mi = 0; mi < 8; mi++) {
            int row = m0 + wm * 128 + mi * 16 + lr4;
            #pragma unroll
            for (int e = 0; e < 4; e++) {
                pre_act[(size_t)(row + e) * D_DIM + col] = acc[mi][nj][e] + bias;
            }
        }
    }
}

__global__ void collect_kernel(const float* __restrict__ pre_act,
                               int* __restrict__ cnt,
                               int* __restrict__ cidx,
                               float* __restrict__ cval) {
    int i = blockIdx.x * blockDim.x + threadIdx.x;
    float4 v = *(const float4*)&pre_act[(size_t)i * 4];
    float fv[4] = {v.x, v.y, v.z, v.w};
    int base = i * 4;
    #pragma unroll
    for (int e = 0; e < 4; e++) {
        if (fv[e] > COLLECT_THRESH) {
            int idx = base + e;
            int b = idx >> 16;
            int d = idx & (D_DIM - 1);
            int p = atomicAdd(&cnt[b], 1);
            if (p < CAND_CAP) {
                cidx[b * CAND_CAP + p] = d;
                cval[b * CAND_CAP + p] = fv[e];
            }
        }
    }
}

__global__ void __launch_bounds__(256) select_topk_kernel(
        const float* __restrict__ x, const float* __restrict__ pre_bias,
        const float* __restrict__ Wenc, const float* __restrict__ b_enc,
        const int* __restrict__ cnt, const int* __restrict__ cidx, const float* __restrict__ cval,
        float* __restrict__ out_vals, float* __restrict__ out_idx) {
    __shared__ float s_val[CAND_CAP];
    __shared__ int   s_idx[CAND_CAP];
    __shared__ __align__(16) float s_x[H_DIM];
    __shared__ double s_dv[RECOMP_PAD];
    __shared__ int    s_di[RECOMP_PAD];

    const int b = blockIdx.x;
    const int tid = threadIdx.x;

    for (int i = tid; i < H_DIM / 4; i += 256) {
        float4 xv = *(const float4*)&x[(size_t)b * H_DIM + i * 4];
        float4 pb = *(const float4*)&pre_bias[i * 4];
        xv.x -= pb.x; xv.y -= pb.y; xv.z -= pb.z; xv.w -= pb.w;
        *(float4*)&s_x[i * 4] = xv;
    }
    const int n = min(cnt[b], CAND_CAP);
    for (int i = tid; i < CAND_CAP; i += 256) {
        if (i < n) { s_val[i] = cval[b * CAND_CAP + i]; s_idx[i] = cidx[b * CAND_CAP + i]; }
        else       { s_val[i] = -1e30f;                 s_idx[i] = 0x7FFFFFFF; }
    }
    __syncthreads();

    for (int k = 2; k <= CAND_CAP; k <<= 1) {
        for (int j = k >> 1; j > 0; j >>= 1) {
            int p = tid;
            int i1 = (p / j) * 2 * j + (p % j);
            int i2 = i1 + j;
            bool up = ((i1 & k) == 0);
            float v1 = s_val[i1], v2 = s_val[i2];
            int  d1 = s_idx[i1],  d2 = s_idx[i2];
            bool before12 = (v1 > v2) || (v1 == v2 && d1 < d2);
            bool before21 = (v2 > v1) || (v2 == v1 && d2 < d1);
            bool sw = up ? before21 : before12;
            __syncthreads();
            if (sw) { s_val[i1] = v2; s_val[i2] = v1; s_idx[i1] = d2; s_idx[i2] = d1; }
            __syncthreads();
        }
    }

    const int T = min(RECOMP, n);
    double dv = -1e300;
    int di = 0x7FFFFFFF;
    if (tid < T) {
        di = s_idx[tid];
        const float* wr = &Wenc[(size_t)di * H_DIM];
        double a0 = 0, a1 = 0, a2 = 0, a3 = 0;
        for (int h = 0; h < H_DIM; h += 4) {
            float4 wv = *(const float4*)&wr[h];
            float4 xv = *(const float4*)&s_x[h];
            a0 += (double)xv.x * (double)wv.x;
            a1 += (double)xv.y * (double)wv.y;
            a2 += (double)xv.z * (double)wv.z;
            a3 += (double)xv.w * (double)wv.w;
        }
        dv = ((a0 + a1) + (a2 + a3)) + (double)b_enc[di];
    }
    __syncthreads();
    if (tid < RECOMP_PAD) { s_dv[tid] = (tid < T) ? dv : -1e300; s_di[tid] = di; }

    for (int k = 2; k <= RECOMP_PAD; k <<= 1) {
        for (int j = k >> 1; j > 0; j >>= 1) {
            __syncthreads();
            if (tid < RECOMP_PAD / 2) {
                int p = tid;
                int i1 = (p / j) * 2 * j + (p % j);
                int i2 = i1 + j;
                bool up = ((i1 & k) == 0);
                double v1 = s_dv[i1], v2 = s_dv[i2];
                int  d1 = s_di[i1],  d2 = s_di[i2];
                bool before12 = (v1 > v2) || (v1 == v2 && d1 < d2);
                bool before21 = (v2 > v1) || (v2 == v1 && d2 < d1);
                bool sw = up ? before21 : before12;
                if (sw) { s_dv[i1] = v2; s_dv[i2] = v1; s_di[i1] = d2; s_di[i2] = d1; }
            }
        }
    }
    __syncthreads();
    if (tid < K_TOP) {
        double v = s_dv[tid];
        out_vals[b * K_TOP + tid] = (float)(v > 0.0 ? v : 0.0);
        out_idx[b * K_TOP + tid]  = (float)s_di[tid];
    }
}

__global__ void __launch_bounds__(64) decode_kernel(
        const float* __restrict__ out_vals,
        const float* __restrict__ out_idx,
        const float* __restrict__ Wdec,
        const float* __restrict__ pre_bias,
        float* __restrict__ x_hat_t) {
    __shared__ float2 s_vi[64 * 64];
    const int lane = threadIdx.x;
    const int s0 = (blockIdx.x >> 3) & 15;

    for (int i = lane; i < 64 * 64; i += 64) {
        int j = i >> 6, bb = i & 63;
        int b = s0 * 64 + bb;
        float v = out_vals[b * K_TOP + j];
        int id = (int)out_idx[b * K_TOP + j];
        s_vi[i] = make_float2(v, __int_as_float(id << 2));
    }
    __syncthreads();

    const int b = s0 * 64 + lane;
    for (int wi = blockIdx.x; wi < H_DIM * 16; wi += 1280) {
        const int h = (wi & 7) + ((wi >> 7) << 3);
        const char* wr = (const char*)(Wdec + (size_t)h * D_DIM);
        float acc = 0.0f;
        #pragma unroll 8
        for (int j = 0; j < K_TOP; j++) {
            float2 vi = s_vi[j * 64 + lane];
            acc = fmaf(vi.x, *(const float*)(wr + __float_as_int(vi.y)), acc);
        }
        x_hat_t[(size_t)h * B_DIM + b] = acc + pre_bias[h];
    }
}

__global__ void __launch_bounds__(256) transpose_kernel(const float* __restrict__ xt,
                                                        float* __restrict__ x_hat) {
    __shared__ float tile[64][65];
    const int hb = blockIdx.x * 64;
    const int bb = blockIdx.y * 64;
    const int tc = threadIdx.x & 63, tr = threadIdx.x >> 6;
    #pragma unroll
    for (int r = tr; r < 64; r += 4)
        tile[r][tc] = xt[(size_t)(hb + r) * B_DIM + bb + tc];
    __syncthreads();
    #pragma unroll
    for (int r = tr; r < 64; r += 4)
        x_hat[(size_t)(bb + r) * H_DIM + hb + tc] = tile[tc][r];
}

// ---------------- launch ----------------
extern "C" void kernel_launch(void* const* d_in, const int* in_sizes, int n_in,
                              void* d_out, int out_size, void* d_ws, size_t ws_size,
                              hipStream_t stream) {
    const float* x        = (const float*)d_in[0];
    const float* W_enc    = (const float*)d_in[1];
    const float* b_enc    = (const float*)d_in[2];
    const float* W_dec    = (const float*)d_in[3];
    const float* pre_bias = (const float*)d_in[4];

    float* out = (float*)d_out;
    float* x_hat    = out;
    float* top_vals = out + (size_t)B_DIM * H_DIM;
    float* top_idx  = top_vals + (size_t)B_DIM * K_TOP;
    float* pre_act  = top_idx + (size_t)B_DIM * K_TOP;

    // workspace layout
    unsigned short* xc = (unsigned short*)d_ws;                               // [0, 8MB)
    int*   cidx  = (int*)((char*)d_ws + (size_t)B_DIM * H_DIM * 2);           // [8, 10MB)
    float* cval  = (float*)((char*)cidx + (size_t)B_DIM * CAND_CAP * 4);      // [10, 12MB)
    int*   cnt   = (int*)((char*)cval + (size_t)B_DIM * CAND_CAP * 4);        // [12MB, +4KB)
    float* xhatt = (float*)((char*)cnt + 4096);                               // fallback only
    const size_t WDT_OFF = 32ull << 20;
    unsigned short* wdecT = (unsigned short*)((char*)d_ws + WDT_OFF);         // 512 MB
    const bool big_ws = ws_size >= WDT_OFF + ((size_t)D_DIM * H_DIM * 2) + (1 << 20);

    hipMemsetAsync(cnt, 0, B_DIM * sizeof(int), stream);

    convert_x_kernel<<<(B_DIM * H_DIM / 4) / 256, 256, 0, stream>>>(x, pre_bias, xc);

    if (big_ws) {
        gemm_twdec_kernel<<<NGEMM_BLK + NTW_BLK, 256, 0, stream>>>(
            xc, W_enc, b_enc, pre_act, cnt, cidx, cval, W_dec, wdecT);
        select_decode_kernel<<<B_DIM, 256, 0, stream>>>(
            x, pre_bias, W_enc, b_enc, cnt, cidx, cval, wdecT,
            top_vals, top_idx, x_hat);
    } else {
        dim3 ggrid(B_DIM / G_BM, D_DIM / G_BN);
        gemm_enc_kernel<<<ggrid, 256, 0, stream>>>(xc, W_enc, b_enc, pre_act);
        collect_kernel<<<(B_DIM * (D_DIM / 4)) / 256, 256, 0, stream>>>(pre_act, cnt, cidx, cval);
        select_topk_kernel<<<B_DIM, 256, 0, stream>>>(x, pre_bias, W_enc, b_enc, cnt, cidx, cval,
                                                      top_vals, top_idx);
        decode_kernel<<<1280, 64, 0, stream>>>(top_vals, top_idx, W_dec, pre_bias, xhatt);
        dim3 tgrid(H_DIM / 64, B_DIM / 64);
        transpose_kernel<<<tgrid, 256, 0, stream>>>(xhatt, x_hat);
    }
}